// Round 9
// baseline (483.625 us; speedup 1.0000x reference)
//
#include <hip/hip_runtime.h>
#include <math.h>

#define LSEQ 1280
#define L0SEQ 1250
#define DM 64
#define NHEADS 4
#define DHD 16
#define NHASH 4
#define NBUK 20
#define NCHUNK 80
#define FFD 256
#define NBATCH 16
#define NBH 64

#define XSZ (NBATCH*LSEQ*DM)        // 1310720
#define QKSZ (NBH*LSEQ*DHD)         // 1310720
#define OHSZ (NBH*NHASH*LSEQ*DHD)   // 5242880
#define SLSZ (NBH*NHASH*LSEQ)       // 327680

typedef __attribute__((ext_vector_type(8))) short frag_ab;   // 8 bf16
typedef __attribute__((ext_vector_type(4))) float frag_c;    // 4 fp32

union FU4 { uint4 v; frag_ab f; };

__device__ __forceinline__ unsigned rnbf(float x){
    unsigned b = __float_as_uint(x);
    return (b + 0x7fffu + ((b >> 16) & 1u)) >> 16;
}
__device__ __forceinline__ float bf2f(unsigned h){ return __uint_as_float(h << 16); }
__device__ __forceinline__ unsigned rot16(unsigned x){ return (x >> 16) | (x << 16); }
__device__ __forceinline__ uint4 rot16v(uint4 a){
    uint4 r; r.x=rot16(a.x); r.y=rot16(a.y); r.z=rot16(a.z); r.w=rot16(a.w); return r;
}

// exact triple split (truncation): x = h + m + l
__device__ __forceinline__ void split3(float x, unsigned& h, unsigned& m, unsigned& l){
    unsigned bx = __float_as_uint(x);
    h = bx >> 16;
    float r = x - __uint_as_float(bx & 0xffff0000u);
    unsigned br = __float_as_uint(r);
    m = br >> 16;
    float r2 = r - __uint_as_float(br & 0xffff0000u);
    l = __float_as_uint(r2) >> 16;
}

// 2-limb split packed (h | m<<16) in one v_perm (truncation)
__device__ __forceinline__ unsigned pack_hm(float x){
    unsigned bx = __float_as_uint(x);
    float r = x - __uint_as_float(bx & 0xffff0000u);
    return __builtin_amdgcn_perm(__float_as_uint(r), bx, 0x07060302u);
}

// 2-limb ROUNDED split (residual <= 2^-18 |x|)
__device__ __forceinline__ unsigned pack_hm_rn(float x){
    unsigned h = rnbf(x);
    unsigned m = rnbf(x - bf2f(h));
    return h | (m << 16);
}

// 3-limb split: hm = h|(m<<16) packed via perm; l as bare u16
__device__ __forceinline__ void split_hml(float x, unsigned& hm, unsigned& l){
    unsigned bx = __float_as_uint(x);
    float r = x - __uint_as_float(bx & 0xffff0000u);
    unsigned br = __float_as_uint(r);
    hm = __builtin_amdgcn_perm(br, bx, 0x07060302u);
    float r2 = r - __uint_as_float(br & 0xffff0000u);
    l = __float_as_uint(r2) >> 16;
}

// gelu with A&S 7.1.26 erf (|err| <= 1.5e-7)
__device__ __forceinline__ float gelu_fast(float x){
    float ax = fabsf(x) * 0.70710678118654752f;
    float t = __builtin_amdgcn_rcpf(1.f + 0.3275911f*ax);
    float poly = ((((1.061405429f*t - 1.453152027f)*t + 1.421413741f)*t
                   - 0.284496736f)*t + 0.254829592f)*t;
    float e = 1.f - poly * __expf(-ax*ax);
    float er = __uint_as_float((__float_as_uint(e) & 0x7fffffffu) |
                               (__float_as_uint(x) & 0x80000000u));
    return 0.5f*x*(1.f + er);
}

// ---------------- init: embed (blocks 0..5119) + weight pre-split (blocks 5120..5695) ----------------
__global__ __launch_bounds__(256) void k_init(
    const float* __restrict__ wave, const float* __restrict__ in_w, const float* __restrict__ in_b,
    float* __restrict__ x1, float* __restrict__ x2,
    const float* __restrict__ wo_w, const float* __restrict__ w1,
    const float* __restrict__ w2, unsigned* __restrict__ wsplit)
{
    if (blockIdx.x < 5120) {
        int idx = blockIdx.x * 256 + threadIdx.x;
        int d = idx & 63;
        int t = idx >> 6;
        int b = t / LSEQ;
        int tt = t % LSEQ;
        float v0 = 0.f, v1 = 0.f;
        if (tt < L0SEQ) {
            v0 = wave[(size_t)(b*2+0)*L0SEQ + tt];
            v1 = wave[(size_t)(b*2+1)*L0SEQ + tt];
        }
        float x = v0 * in_w[d] + v1 * in_w[64 + d] + in_b[d];
        x1[idx] = x;
        x2[idx] = x;
    } else {
        int gid = (blockIdx.x - 5120) * 256 + threadIdx.x;   // < 147456 exactly
        int l = gid / 36864;
        int r = gid % 36864;
        float src; unsigned* dst; int idx; int stride;
        if (r < 4096) {                 // wo: K=64, N=64
            int k = r >> 6, n = r & 63;
            src = wo_w[l*4096 + k*64 + n];
            dst = wsplit + l*8192;
            idx = (((k>>4)*4 + (n>>4))*16 + (n&15))*16 + (k&15);
            stride = 4096;
        } else if (r < 20480) {         // w1: K=64, N=256
            int rr = r - 4096;
            int k = rr >> 8, n = rr & 255;
            src = w1[l*16384 + k*256 + n];
            dst = wsplit + 32768 + l*32768;
            idx = (((k>>4)*16 + (n>>4))*16 + (n&15))*16 + (k&15);
            stride = 16384;
        } else {                        // w2: K=256, N=64
            int rr = r - 20480;
            int k = rr >> 6, n = rr & 63;
            src = w2[l*16384 + k*64 + n];
            dst = wsplit + 163840 + l*32768;
            idx = (((k>>4)*4 + (n>>4))*16 + (n&15))*16 + (k&15);
            stride = 16384;
        }
        unsigned h, m, lo;
        split3(src, h, m, lo);
        dst[idx]          = h | (m<<16);
        dst[idx + stride] = lo | (h<<16);
    }
}

// ---------------- LN + QK/V proj + bucketing + pre-split (R6 passing version) ----------------
__global__ __launch_bounds__(256) void k_qkv(
    const float* __restrict__ x2, const float* __restrict__ g, const float* __restrict__ bta,
    const float* __restrict__ wqk, const float* __restrict__ wv, const float* __restrict__ rot,
    unsigned* __restrict__ qkvs, int* __restrict__ buckets)
{
    __shared__ float xln[16][68];
    __shared__ float qkt[16][68];
    __shared__ float vvt[16][68];
    __shared__ float rots[640];
    int tid = threadIdx.x;
    int b  = blockIdx.x / 80;
    int t0 = (blockIdx.x % 80) * 16;
    int tok = tid >> 4;
    int cg  = tid & 15;
    int c4  = cg * 4;

    for (int i = tid; i < 640; i += 256) rots[i] = rot[i];

    float4 xv4 = *(const float4*)&x2[((size_t)b*LSEQ + t0 + tok)*DM + c4];
    float s = xv4.x + xv4.y + xv4.z + xv4.w;
    float ss = xv4.x*xv4.x + xv4.y*xv4.y + xv4.z*xv4.z + xv4.w*xv4.w;
    s  += __shfl_xor(s,1);  s  += __shfl_xor(s,2);  s  += __shfl_xor(s,4);  s  += __shfl_xor(s,8);
    ss += __shfl_xor(ss,1); ss += __shfl_xor(ss,2); ss += __shfl_xor(ss,4); ss += __shfl_xor(ss,8);
    float m = s * (1.f/64.f);
    float vr = ss * (1.f/64.f) - m*m;
    float rstd = 1.f / sqrtf(vr + 1e-5f);
    {
        float4 g4 = *(const float4*)&g[c4];
        float4 b4 = *(const float4*)&bta[c4];
        float4 o;
        o.x = (xv4.x-m)*rstd*g4.x + b4.x;
        o.y = (xv4.y-m)*rstd*g4.y + b4.y;
        o.z = (xv4.z-m)*rstd*g4.z + b4.z;
        o.w = (xv4.w-m)*rstd*g4.w + b4.w;
        *(float4*)&xln[tok][c4] = o;
    }
    __syncthreads();

    float aq[4] = {0,0,0,0}, av[4] = {0,0,0,0};
    for (int f = 0; f < 64; f++) {
        float4 wq4 = *(const float4*)&wqk[f*64 + c4];
        float4 wv4 = *(const float4*)&wv [f*64 + c4];
        float xv = xln[tok][f];
        aq[0] += xv*wq4.x; aq[1] += xv*wq4.y; aq[2] += xv*wq4.z; aq[3] += xv*wq4.w;
        av[0] += xv*wv4.x; av[1] += xv*wv4.y; av[2] += xv*wv4.z; av[3] += xv*wv4.w;
    }
    *(float4*)&qkt[tok][c4] = *(float4*)aq;
    *(float4*)&vvt[tok][c4] = *(float4*)av;
    __syncthreads();

    int p = tid >> 2;
    int ptok = p >> 2, head = p & 3;
    int sub = tid & 3;
    int e0 = sub * 4;
    int t = t0 + ptok;
    float4 qf4 = *(const float4*)&qkt[ptok][head*16 + e0];
    float nsq = qf4.x*qf4.x + qf4.y*qf4.y + qf4.z*qf4.z + qf4.w*qf4.w;
    nsq += __shfl_xor(nsq,1); nsq += __shfl_xor(nsq,2);
    float inv = 1.f / fmaxf(sqrtf(nsq), 1e-12f);
    float qe[4] = {qf4.x, qf4.y, qf4.z, qf4.w};
    unsigned wq[4], wk[4];
    #pragma unroll
    for (int i=0;i<4;i++){
        float xq = qe[i]*0.25f;
        unsigned qh = rnbf(xq);
        unsigned ql = rnbf(xq - bf2f(qh));
        wq[i] = qh | (ql<<16);
        float xk = qe[i]*inv;
        unsigned kh = rnbf(xk);
        unsigned kl = rnbf(xk - bf2f(kh));
        wk[i] = kh | (kl<<16);
    }
    float4 vf4 = *(const float4*)&vvt[ptok][head*16 + e0];
    unsigned wv1[4];
    wv1[0] = pack_hm_rn(vf4.x); wv1[1] = pack_hm_rn(vf4.y);
    wv1[2] = pack_hm_rn(vf4.z); wv1[3] = pack_hm_rn(vf4.w);
    size_t sb = (((size_t)(b*NHEADS+head))*LSEQ + t)*64;
    *(uint4*)&qkvs[sb + e0]      = *(uint4*)wq;
    *(uint4*)&qkvs[sb + 16 + e0] = *(uint4*)wk;
    *(uint4*)&qkvs[sb + 32 + e0] = *(uint4*)wv1;

    float qf[16];
    {
        float4 a0 = *(const float4*)&qkt[ptok][head*16 + 0];
        float4 a1 = *(const float4*)&qkt[ptok][head*16 + 4];
        float4 a2 = *(const float4*)&qkt[ptok][head*16 + 8];
        float4 a3 = *(const float4*)&qkt[ptok][head*16 + 12];
        qf[0]=a0.x; qf[1]=a0.y; qf[2]=a0.z; qf[3]=a0.w;
        qf[4]=a1.x; qf[5]=a1.y; qf[6]=a1.z; qf[7]=a1.w;
        qf[8]=a2.x; qf[9]=a2.y; qf[10]=a2.z; qf[11]=a2.w;
        qf[12]=a3.x; qf[13]=a3.y; qf[14]=a3.z; qf[15]=a3.w;
    }
    int nh = sub;
    float rv[10];
    #pragma unroll
    for (int i=0;i<10;i++) {
        float acc = 0.f;
        #pragma unroll
        for (int f=0; f<16; f++) acc += qf[f]*rots[(f*NHASH+nh)*10 + i];
        rv[i] = acc;
    }
    float best = rv[0]; int bi = 0;
    #pragma unroll
    for (int i=1;i<10;i++) if (rv[i] > best) { best = rv[i]; bi = i; }
    #pragma unroll
    for (int i=0;i<10;i++) if (-rv[i] > best) { best = -rv[i]; bi = 10+i; }
    buckets[((size_t)(b*NHEADS+head)*NHASH + nh)*LSEQ + t] = bi;
}

// ---------------- counting sort v2 ----------------
__global__ __launch_bounds__(256) void k_sort(
    const int* __restrict__ buckets, int* __restrict__ sorted)
{
    __shared__ unsigned long long masks[20][20];   // [chunk][bucket]
    __shared__ int pre[20][20];                    // prefix over chunks<ch per bucket
    __shared__ int startl[20];
    int tid = threadIdx.x;
    int w = tid >> 6, lane = tid & 63;
    int gidx = blockIdx.x;
    const int* bk = buckets + (size_t)gidx * LSEQ;
    int* dst = sorted + (size_t)gidx * LSEQ;

    int myb[5];
    #pragma unroll
    for (int i = 0; i < 5; i++) {
        int ch = w*5 + i;
        int bv = bk[ch*64 + lane];
        myb[i] = bv;
        #pragma unroll
        for (int b2 = 0; b2 < 20; b2++) {
            unsigned long long m2 = __ballot(bv == b2);
            if (lane == b2) masks[ch][b2] = m2;
        }
    }
    __syncthreads();
    if (tid < 20) {
        int run = 0;
        for (int ch = 0; ch < 20; ch++) {
            pre[ch][tid] = run;
            run += __popcll(masks[ch][tid]);
        }
        startl[tid] = run;          // total count for bucket tid (temp)
    }
    __syncthreads();
    if (tid == 0) {
        int acc = 0;
        for (int b2 = 0; b2 < 20; b2++) { int t = startl[b2]; startl[b2] = acc; acc += t; }
    }
    __syncthreads();
    unsigned long long below = (lane == 63) ? 0x7fffffffffffffffull
                                            : ((1ull << lane) - 1ull);
    #pragma unroll
    for (int i = 0; i < 5; i++) {
        int ch = w*5 + i;
        int bv = myb[i];
        int rank = startl[bv] + pre[ch][bv] + __popcll(masks[ch][bv] & below);
        dst[rank] = ch*64 + lane;
    }
}

// ---------------- chunked attention v14b (R6 passing version, unchanged) ----------------
__global__ __launch_bounds__(256) void k_attn(
    const unsigned* __restrict__ qkvs,
    const int* __restrict__ sorted, float* __restrict__ o_hash, float* __restrict__ slog)
{
    __shared__ __align__(16) unsigned SM[5312];            // 21248 B -> 7 blocks/CU
    unsigned* Va1 = SM;                                    // 2624 u32 [kt8][dh16][key16] strides 328/20
    unsigned* Ka1 = SM + 2624;                             // 2560 u32 [key128][16] stride 20 (phase 1)
    unsigned* Pa1 = SM + 2624;                             // phase 2 alias (P h|m)
    int* kposS = (int*)(SM + 5184);                        // 128 ints

    int tid = threadIdx.x;
    int bh = blockIdx.x & 63;          // XCD swizzle: same bh -> same XCD (64 % 8 == 0)
    int c  = blockIdx.x >> 6;
    int h  = c / NBUK, cc = c % NBUK;
    int cp = (c + NCHUNK - 1) % NCHUNK;
    int hp = cp / NBUK, ccp = cp % NBUK;

    int key = tid & 127;
    int pos = (key < 64)
        ? sorted[((size_t)bh*NHASH + h)*LSEQ + cc*64 + key]
        : sorted[((size_t)bh*NHASH + hp)*LSEQ + ccp*64 + (key-64)];
    size_t srow = ((size_t)bh*LSEQ + pos)*64;
    if (tid < 128) {
        kposS[key] = pos;
        const uint4* kr = (const uint4*)(qkvs + srow + 16);
        #pragma unroll
        for (int e4=0; e4<4; e4++)
            *(uint4*)&Ka1[key*20 + e4*4] = kr[e4];
    } else {
        const uint4* v1r = (const uint4*)(qkvs + srow + 32);
        int kt = key >> 4, jl = key & 15;
        int lb = kt*328 + jl;
        #pragma unroll
        for (int e4=0; e4<4; e4++){
            uint4 a = v1r[e4];
            unsigned aa[4] = {a.x,a.y,a.z,a.w};
            #pragma unroll
            for (int i=0;i<4;i++){
                int d = e4*4 + i;
                Va1[lb + d*20] = aa[i];
            }
        }
    }
    __syncthreads();

    int w = tid >> 6, lane = tid & 63;
    int quad = lane >> 4, col = lane & 15;

    int qgpos = kposS[16*w + col];
    FU4 QA;
    QA.v = *(const uint4*)(qkvs + ((size_t)bh*LSEQ + qgpos)*64 + quad*4);
    frag_ab qA = QA.f;

    frag_c acc[8];
    #pragma unroll
    for (int nt=0; nt<8; nt++){
        FU4 B1, B2;
        B1.v = *(const uint4*)&Ka1[(nt*16+col)*20 + 4*quad];
        B2.v = rot16v(B1.v);
        frag_c a = {0.f,0.f,0.f,0.f};
        a = __builtin_amdgcn_mfma_f32_16x16x32_bf16(qA, B1.f, a, 0, 0, 0);
        a = __builtin_amdgcn_mfma_f32_16x16x32_bf16(qA, B2.f, a, 0, 0, 0);
        acc[nt] = a;
    }
    int qp[4];
    #pragma unroll
    for (int reg=0; reg<4; reg++) qp[reg] = kposS[16*w + quad*4 + reg];

    #pragma unroll
    for (int nt=0; nt<8; nt++) if (nt == w) {
        #pragma unroll
        for (int reg=0; reg<4; reg++)
            acc[nt][reg] = (col == quad*4 + reg) ? -5e4f : acc[nt][reg];
    }
    if (cc == 0) {
        #pragma unroll
        for (int nt=4; nt<8; nt++){
            int kp2 = kposS[nt*16 + col];
            #pragma unroll
            for (int reg=0; reg<4; reg++)
                if (kp2 == qp[reg]) acc[nt][reg] = -5e4f;
        }
    }

    float mx[4] = {-3.4e38f,-3.4e38f,-3.4e38f,-3.4e38f};
    #pragma unroll
    for (int nt=0; nt<8; nt++)
        #pragma unroll
        for (int reg=0; reg<4; reg++) mx[reg] = fmaxf(mx[reg], acc[nt][reg]);
    #pragma unroll
    for (int reg=0; reg<4; reg++){
        float m2 = mx[reg];
        m2 = fmaxf(m2, __shfl_xor(m2, 1)); m2 = fmaxf(m2, __shfl_xor(m2, 2));
        m2 = fmaxf(m2, __shfl_xor(m2, 4)); m2 = fmaxf(m2, __shfl_xor(m2, 8));
        mx[reg] = m2;
    }
    float sm2[4] = {0.f,0.f,0.f,0.f};
    #pragma unroll
    for (int nt=0; nt<8; nt++)
        #pragma unroll
        for (int reg=0; reg<4; reg++){
            float e = __expf(acc[nt][reg] - mx[reg]);
            acc[nt][reg] = e; sm2[reg] += e;
        }
    #pragma unroll
    for (int reg=0; reg<4; reg++){
        float s2 = sm2[reg];
        s2 += __shfl_xor(s2, 1); s2 += __shfl_xor(s2, 2);
        s2 += __shfl_xor(s2, 4); s2 += __shfl_xor(s2, 8);
        sm2[reg] = s2;
    }
    float invs[4];
    #pragma unroll
    for (int reg=0; reg<4; reg++) invs[reg] = __builtin_amdgcn_rcpf(sm2[reg]);
    if (col == 0) {
        #pragma unroll
        for (int reg=0; reg<4; reg++)
            slog[((size_t)bh*NHASH + h)*LSEQ + qp[reg]] = mx[reg] + __logf(sm2[reg]);
    }

    frag_c o = {0.f,0.f,0.f,0.f};
    __syncthreads();   // Ka1 dead -> Pa1 alias safe
    #pragma unroll
    for (int pass=0; pass<4; pass++){
        #pragma unroll
        for (int t2=0; t2<2; t2++){
            int nt = pass*2 + t2;
            #pragma unroll
            for (int reg=0; reg<4; reg++){
                int idx = t2*1280 + (16*w + 4*quad + reg)*20 + col;
                Pa1[idx] = pack_hm(acc[nt][reg]);
            }
        }
        __syncthreads();
        #pragma unroll
        for (int t2=0; t2<2; t2++){
            int ktg = pass*2 + t2;
            FU4 A1, B1, B2;
            int pidx = t2*1280 + (16*w + col)*20 + 4*quad;
            A1.v = *(const uint4*)&Pa1[pidx];
            int vidx = ktg*328 + col*20 + 4*quad;
            B1.v = *(const uint4*)&Va1[vidx];
            B2.v = rot16v(B1.v);
            o = __builtin_amdgcn_mfma_f32_16x16x32_bf16(A1.f, B1.f, o, 0, 0, 0);
            o = __builtin_amdgcn_mfma_f32_16x16x32_bf16(A1.f, B2.f, o, 0, 0, 0);
        }
        if (pass < 3) __syncthreads();
    }
    size_t obase = ((size_t)bh*NHASH + h)*LSEQ;
    #pragma unroll
    for (int reg=0; reg<4; reg++)
        o_hash[(obase + qp[reg])*DHD + col] = o[reg] * invs[reg];
}

// ---------------- fused tail v9: w2 full-K per warp (isolated; red reduction eliminated) ----------------
__global__ __launch_bounds__(256) void k_tail(
    const float* __restrict__ o_hash, const float* __restrict__ slog,
    const unsigned* __restrict__ wo_s, const float* __restrict__ wo_b,
    const float* __restrict__ g2, const float* __restrict__ b2t,
    const unsigned* __restrict__ w1_s, const float* __restrict__ b1,
    const unsigned* __restrict__ w2_s, const float* __restrict__ b2f,
    float* __restrict__ x1, float* __restrict__ x2,
    const float* __restrict__ out_w, const float* __restrict__ out_b,
    float* __restrict__ y, int do_out)
{
    __shared__ unsigned cA1[1024];          // 4 KB: combine h|m; later LN h|m
    __shared__ unsigned short cA2h[1024];   // 2 KB: combine l; later LN l
    __shared__ unsigned gA1[4096];          // 16 KB: gelu h|m per wave
    __shared__ unsigned short gA2h[4096];   // 8 KB: gelu l per wave
    __shared__ float lnS[64], lnQ[64];      // 0.5 KB

    int tid = threadIdx.x;
    int b  = blockIdx.x / 80;
    int t0 = (blockIdx.x % 80) * 16;
    int w = tid >> 6, lane = tid & 63;
    int quad = lane >> 4, col = lane & 15;
    int cg = w*16 + col;

    float x1pre[4], x2pre[4];
    #pragma unroll
    for (int reg=0; reg<4; reg++){
        size_t xi = ((size_t)b*LSEQ + t0 + quad*4 + reg)*DM + cg;
        x1pre[reg] = x1[xi];
        x2pre[reg] = x2[xi];
    }
    float wb_pre  = wo_b[cg];
    float gv_pre  = g2[cg];
    float bv_pre  = b2t[cg];
    float bbf_pre = b2f[cg];
    float ow_pre  = out_w[cg];
    float b1v[4];
    #pragma unroll
    for (int ntl=0; ntl<4; ntl++) b1v[ntl] = b1[(w*4 + ntl)*16 + col];

    {
        int tok = tid >> 4;
        int dg  = tid & 15;
        int d0  = dg * 4;
        int kt  = dg >> 2;
        int t = t0 + tok;
        int bh = b*NHEADS + kt;
        float sl[4];
        #pragma unroll
        for (int nh=0; nh<4; nh++) sl[nh] = slog[((size_t)bh*NHASH + nh)*LSEQ + t];
        float mx = fmaxf(fmaxf(sl[0],sl[1]), fmaxf(sl[2],sl[3]));
        float wgt[4]; float wsum = 0.f;
        #pragma unroll
        for (int nh=0; nh<4; nh++){ wgt[nh] = __expf(sl[nh]-mx); wsum += wgt[nh]; }
        float iv = 1.f/wsum;
        float a4[4] = {0.f,0.f,0.f,0.f};
        #pragma unroll
        for (int nh=0; nh<4; nh++){
            float4 oh = *(const float4*)&o_hash[(((size_t)bh*NHASH + nh)*LSEQ + t)*DHD + (d0 & 15)];
            float wn = wgt[nh]*iv;
            a4[0] += wn*oh.x; a4[1] += wn*oh.y; a4[2] += wn*oh.z; a4[3] += wn*oh.w;
        }
        int sw = (tok & 7) << 2;
        unsigned cw1[4], lw[4];
        #pragma unroll
        for (int i=0;i<4;i++) split_hml(a4[i], cw1[i], lw[i]);
        *(uint4*)&cA1[tok*64 + (d0 ^ sw)] = *(uint4*)cw1;
        uint2 lp;
        lp.x = lw[0] | (lw[1]<<16);
        lp.y = lw[2] | (lw[3]<<16);
        *(uint2*)&cA2h[tok*64 + (d0 ^ sw)] = lp;
    }
    __syncthreads();
    FU4 aA1[4], aA2[4];
    {
        int sw = (col & 7) << 2;
        #pragma unroll
        for (int kt=0; kt<4; kt++){
            int word = (kt*16 + quad*4) ^ sw;
            aA1[kt].v = *(const uint4*)&cA1[col*64 + word];
            uint2 zl = *(const uint2*)&cA2h[col*64 + word];
            aA2[kt].v.x = __builtin_amdgcn_perm(zl.x, aA1[kt].v.x, 0x05040100u);
            aA2[kt].v.y = __builtin_amdgcn_perm(zl.x, aA1[kt].v.y, 0x07060100u);
            aA2[kt].v.z = __builtin_amdgcn_perm(zl.y, aA1[kt].v.z, 0x05040100u);
            aA2[kt].v.w = __builtin_amdgcn_perm(zl.y, aA1[kt].v.w, 0x07060100u);
        }
    }

    frag_c awo = {0.f,0.f,0.f,0.f};
    #pragma unroll
    for (int kt=0; kt<4; kt++){
        FU4 B1, B2, B3;
        int bidx = ((kt*4 + w)*16 + col)*16 + quad*4;
        B1.v = *(const uint4*)&wo_s[bidx];
        B2.v = rot16v(B1.v);
        B3.v = *(const uint4*)&wo_s[bidx + 4096];
        awo = __builtin_amdgcn_mfma_f32_16x16x32_bf16(aA1[kt].f, B1.f, awo, 0, 0, 0);
        awo = __builtin_amdgcn_mfma_f32_16x16x32_bf16(aA1[kt].f, B2.f, awo, 0, 0, 0);
        awo = __builtin_amdgcn_mfma_f32_16x16x32_bf16(aA2[kt].f, B3.f, awo, 0, 0, 0);
    }
    float x1n[4];
    float s1[4], s2[4];
    {
        #pragma unroll
        for (int reg=0; reg<4; reg++){
            int rg = t0 + quad*4 + reg;
            size_t xi = ((size_t)b*LSEQ + rg)*DM + cg;
            float xv = x1pre[reg] + awo[reg] + wb_pre;
            x1[xi] = xv;
            x1n[reg] = xv;
            s1[reg] = xv; s2[reg] = xv*xv;
        }
    }
    #pragma unroll
    for (int reg=0; reg<4; reg++){
        float a = s1[reg], q = s2[reg];
        a += __shfl_xor(a,1); a += __shfl_xor(a,2); a += __shfl_xor(a,4); a += __shfl_xor(a,8);
        q += __shfl_xor(q,1); q += __shfl_xor(q,2); q += __shfl_xor(q,4); q += __shfl_xor(q,8);
        s1[reg] = a; s2[reg] = q;
    }
    if (col == 0) {
        #pragma unroll
        for (int reg=0; reg<4; reg++){
            lnS[w*16 + quad*4 + reg] = s1[reg];
            lnQ[w*16 + quad*4 + reg] = s2[reg];
        }
    }
    __syncthreads();   // also orders aA reads (above) before LN writes (below) into cA
    float mean[4], rstd[4];
    #pragma unroll
    for (int reg=0; reg<4; reg++){
        int tok = quad*4 + reg;
        float a = lnS[tok] + lnS[16+tok] + lnS[32+tok] + lnS[48+tok];
        float q = lnQ[tok] + lnQ[16+tok] + lnQ[32+tok] + lnQ[48+tok];
        mean[reg] = a*(1.f/64.f);
        float var = q*(1.f/64.f) - mean[reg]*mean[reg];
        rstd[reg] = 1.f/sqrtf(var + 1e-5f);
    }
    {
        #pragma unroll
        for (int reg=0; reg<4; reg++){
            int row = quad*4 + reg;
            float xv = (x1n[reg]-mean[reg])*rstd[reg]*gv_pre + bv_pre;
            unsigned hm_, l_;
            split_hml(xv, hm_, l_);
            int word = cg ^ ((row & 7) << 2);
            cA1[row*64 + word] = hm_;
            cA2h[row*64 + word] = (unsigned short)l_;
        }
    }
    __syncthreads();
    FU4 xa1[4], xa2[4];
    {
        int sw = (col & 7) << 2;
        #pragma unroll
        for (int kt=0; kt<4; kt++){
            int word = (kt*16 + quad*4) ^ sw;
            xa1[kt].v = *(const uint4*)&cA1[col*64 + word];
            uint2 zl = *(const uint2*)&cA2h[col*64 + word];
            xa2[kt].v.x = __builtin_amdgcn_perm(zl.x, xa1[kt].v.x, 0x05040100u);
            xa2[kt].v.y = __builtin_amdgcn_perm(zl.x, xa1[kt].v.y, 0x07060100u);
            xa2[kt].v.z = __builtin_amdgcn_perm(zl.y, xa1[kt].v.z, 0x05040100u);
            xa2[kt].v.w = __builtin_amdgcn_perm(zl.y, xa1[kt].v.w, 0x07060100u);
        }
    }

    unsigned* myg1 = gA1 + w*1024;
    unsigned short* myg2h = gA2h + w*1024;
    #pragma unroll
    for (int ntl=0; ntl<4; ntl++){
        int nt = w*4 + ntl;
        frag_c a = {0.f,0.f,0.f,0.f};
        #pragma unroll
        for (int kt=0; kt<4; kt++){
            FU4 B1, B2, B3;
            int bidx = ((kt*16 + nt)*16 + col)*16 + quad*4;
            B1.v = *(const uint4*)&w1_s[bidx];
            B2.v = rot16v(B1.v);
            B3.v = *(const uint4*)&w1_s[bidx + 16384];
            a = __builtin_amdgcn_mfma_f32_16x16x32_bf16(xa1[kt].f, B1.f, a, 0, 0, 0);
            a = __builtin_amdgcn_mfma_f32_16x16x32_bf16(xa1[kt].f, B2.f, a, 0, 0, 0);
            a = __builtin_amdgcn_mfma_f32_16x16x32_bf16(xa2[kt].f, B3.f, a, 0, 0, 0);
        }
        float bb = b1v[ntl];
        #pragma unroll
        for (int reg=0; reg<4; reg++){
            float xx = a[reg] + bb;
            float ge = gelu_fast(xx);
            unsigned hm_, l_;
            split_hml(ge, hm_, l_);
            int row = quad*4 + reg;
            int word = (ntl*16 + col) ^ ((row & 7) << 2);
            myg1[row*64 + word] = hm_;
            myg2h[row*64 + word] = (unsigned short)l_;
        }
    }
    __syncthreads();   // all warps' gelu regions visible
    // w2: each warp computes its own 16 output cols over FULL K=256 (no red reduction).
    // A features kg*16+quad*4+j  <->  B k=kg*16+quad*4+j, n=w*16+col (same packing as w1/wo).
    frag_c aw2 = {0.f,0.f,0.f,0.f};
    {
        int sw = (col & 7) << 2;
        #pragma unroll
        for (int kg=0; kg<16; kg++){
            FU4 A1, A2;
            int base = (kg>>2)*1024 + col*64 + ((((kg&3)*16) + quad*4) ^ sw);
            A1.v = *(const uint4*)&gA1[base];
            uint2 zl = *(const uint2*)&gA2h[base];
            A2.v.x = __builtin_amdgcn_perm(zl.x, A1.v.x, 0x05040100u);
            A2.v.y = __builtin_amdgcn_perm(zl.x, A1.v.y, 0x07060100u);
            A2.v.z = __builtin_amdgcn_perm(zl.y, A1.v.z, 0x05040100u);
            A2.v.w = __builtin_amdgcn_perm(zl.y, A1.v.w, 0x07060100u);
            FU4 B1, B2, B3;
            int bidx = ((kg*4 + w)*16 + col)*16 + quad*4;
            B1.v = *(const uint4*)&w2_s[bidx];
            B2.v = rot16v(B1.v);
            B3.v = *(const uint4*)&w2_s[bidx + 16384];
            aw2 = __builtin_amdgcn_mfma_f32_16x16x32_bf16(A1.f, B1.f, aw2, 0, 0, 0);
            aw2 = __builtin_amdgcn_mfma_f32_16x16x32_bf16(A1.f, B2.f, aw2, 0, 0, 0);
            aw2 = __builtin_amdgcn_mfma_f32_16x16x32_bf16(A2.f, B3.f, aw2, 0, 0, 0);
        }
    }
    float x2f[4];
    {
        #pragma unroll
        for (int reg=0; reg<4; reg++){
            int rg = t0 + quad*4 + reg;
            size_t xi = ((size_t)b*LSEQ + rg)*DM + cg;
            float nv = x2pre[reg] + aw2[reg] + bbf_pre;
            x2[xi] = nv;
            x2f[reg] = nv;
        }
    }
    if (do_out) {
        float part[4];
        #pragma unroll
        for (int reg=0; reg<4; reg++){
            float p = (x1n[reg] + x2f[reg]) * 0.5f * ow_pre;
            p += __shfl_xor(p,1); p += __shfl_xor(p,2); p += __shfl_xor(p,4); p += __shfl_xor(p,8);
            part[reg] = p;
        }
        __syncthreads();
        if (col == 0) {
            #pragma unroll
            for (int reg=0; reg<4; reg++)
                lnS[w*16 + quad*4 + reg] = part[reg];
        }
        __syncthreads();
        if (tid < 16) {
            int t = t0 + tid;
            if (t < L0SEQ) {
                float v2 = lnS[tid] + lnS[16+tid] + lnS[32+tid] + lnS[48+tid];
                y[(size_t)b*L0SEQ + t] = v2 + out_b[0];
            }
        }
    }
}

extern "C" void kernel_launch(void* const* d_in, const int* in_sizes, int n_in,
                              void* d_out, int out_size, void* d_ws, size_t ws_size,
                              hipStream_t stream)
{
    const float* wave  = (const float*)d_in[0];
    const float* in_w  = (const float*)d_in[1];
    const float* in_b  = (const float*)d_in[2];
    const float* ln1_g = (const float*)d_in[3];
    const float* ln1_b = (const float*)d_in[4];
    const float* wqk   = (const float*)d_in[5];
    const float* wv    = (const float*)d_in[6];
    const float* wo_w  = (const float*)d_in[7];
    const float* wo_b  = (const float*)d_in[8];
    const float* rot   = (const float*)d_in[9];
    const float* ln2_g = (const float*)d_in[10];
    const float* ln2_b = (const float*)d_in[11];
    const float* w1    = (const float*)d_in[12];
    const float* b1    = (const float*)d_in[13];
    const float* w2    = (const float*)d_in[14];
    const float* b2    = (const float*)d_in[15];
    const float* out_w = (const float*)d_in[16];
    const float* out_b = (const float*)d_in[17];
    float* y = (float*)d_out;

    float* ws = (float*)d_ws;
    float* x1      = ws;                       // XSZ f32
    float* x2      = x1 + XSZ;                 // XSZ f32
    unsigned* qkvs = (unsigned*)(x2 + XSZ);    // 4*QKSZ u32 (interleaved)
    float* o_hash  = (float*)(qkvs + 4*QKSZ);  // OHSZ f32
    float* slogb   = o_hash + OHSZ;            // SLSZ f32
    int* buckets   = (int*)(slogb + SLSZ);     // SLSZ int
    int* sorted    = buckets + SLSZ;           // SLSZ int
    unsigned* wsplit = (unsigned*)(sorted + SLSZ); // 294912 u32

    k_init<<<5696, 256, 0, stream>>>(wave, in_w, in_b, x1, x2, wo_w, w1, w2, wsplit);
    for (int layer = 0; layer < 4; layer++) {
        k_qkv<<<NBATCH*80, 256, 0, stream>>>(x2, ln1_g + layer*64, ln1_b + layer*64,
                                       wqk + layer*4096, wv + layer*4096, rot + layer*640,
                                       qkvs, buckets);
        k_sort<<<256, 256, 0, stream>>>(buckets, sorted);
        k_attn<<<NBH*NCHUNK, 256, 0, stream>>>(qkvs, sorted, o_hash, slogb);
        k_tail<<<NBATCH*LSEQ/16, 256, 0, stream>>>(o_hash, slogb,
                                        wsplit + layer*8192, wo_b + layer*64,
                                        ln2_g + layer*64, ln2_b + layer*64,
                                        wsplit + 32768 + layer*32768, b1 + layer*256,
                                        wsplit + 163840 + layer*32768, b2 + layer*64,
                                        x1, x2,
                                        out_w, out_b, y, (layer == 3) ? 1 : 0);
    }
}

// Round 10
// 477.208 us; speedup vs baseline: 1.0134x; 1.0134x over previous
//
#include <hip/hip_runtime.h>
#include <math.h>

#define LSEQ 1280
#define L0SEQ 1250
#define DM 64
#define NHEADS 4
#define DHD 16
#define NHASH 4
#define NBUK 20
#define NCHUNK 80
#define FFD 256
#define NBATCH 16
#define NBH 64

#define XSZ (NBATCH*LSEQ*DM)        // 1310720
#define QKSZ (NBH*LSEQ*DHD)         // 1310720
#define OHSZ (NBH*NHASH*LSEQ*DHD)   // 5242880
#define SLSZ (NBH*NHASH*LSEQ)       // 327680

typedef __attribute__((ext_vector_type(8))) short frag_ab;   // 8 bf16
typedef __attribute__((ext_vector_type(4))) float frag_c;    // 4 fp32

union FU4 { uint4 v; frag_ab f; };

__device__ __forceinline__ unsigned rnbf(float x){
    unsigned b = __float_as_uint(x);
    return (b + 0x7fffu + ((b >> 16) & 1u)) >> 16;
}
__device__ __forceinline__ float bf2f(unsigned h){ return __uint_as_float(h << 16); }
__device__ __forceinline__ unsigned rot16(unsigned x){ return (x >> 16) | (x << 16); }
__device__ __forceinline__ uint4 rot16v(uint4 a){
    uint4 r; r.x=rot16(a.x); r.y=rot16(a.y); r.z=rot16(a.z); r.w=rot16(a.w); return r;
}

// exact triple split (truncation): x = h + m + l
__device__ __forceinline__ void split3(float x, unsigned& h, unsigned& m, unsigned& l){
    unsigned bx = __float_as_uint(x);
    h = bx >> 16;
    float r = x - __uint_as_float(bx & 0xffff0000u);
    unsigned br = __float_as_uint(r);
    m = br >> 16;
    float r2 = r - __uint_as_float(br & 0xffff0000u);
    l = __float_as_uint(r2) >> 16;
}

// 2-limb split packed (h | m<<16) in one v_perm (truncation)
__device__ __forceinline__ unsigned pack_hm(float x){
    unsigned bx = __float_as_uint(x);
    float r = x - __uint_as_float(bx & 0xffff0000u);
    return __builtin_amdgcn_perm(__float_as_uint(r), bx, 0x07060302u);
}

// 2-limb ROUNDED split (residual <= 2^-18 |x|)
__device__ __forceinline__ unsigned pack_hm_rn(float x){
    unsigned h = rnbf(x);
    unsigned m = rnbf(x - bf2f(h));
    return h | (m << 16);
}

// 3-limb split: hm = h|(m<<16) packed via perm; l as bare u16
__device__ __forceinline__ void split_hml(float x, unsigned& hm, unsigned& l){
    unsigned bx = __float_as_uint(x);
    float r = x - __uint_as_float(bx & 0xffff0000u);
    unsigned br = __float_as_uint(r);
    hm = __builtin_amdgcn_perm(br, bx, 0x07060302u);
    float r2 = r - __uint_as_float(br & 0xffff0000u);
    l = __float_as_uint(r2) >> 16;
}

// gelu with A&S 7.1.26 erf (|err| <= 1.5e-7)
__device__ __forceinline__ float gelu_fast(float x){
    float ax = fabsf(x) * 0.70710678118654752f;
    float t = __builtin_amdgcn_rcpf(1.f + 0.3275911f*ax);
    float poly = ((((1.061405429f*t - 1.453152027f)*t + 1.421413741f)*t
                   - 0.284496736f)*t + 0.254829592f)*t;
    float e = 1.f - poly * __expf(-ax*ax);
    float er = __uint_as_float((__float_as_uint(e) & 0x7fffffffu) |
                               (__float_as_uint(x) & 0x80000000u));
    return 0.5f*x*(1.f + er);
}

// ---------------- init: embed (blocks 0..5119) + weight pre-split (blocks 5120..5695) ----------------
__global__ __launch_bounds__(256) void k_init(
    const float* __restrict__ wave, const float* __restrict__ in_w, const float* __restrict__ in_b,
    float* __restrict__ x1, float* __restrict__ x2,
    const float* __restrict__ wo_w, const float* __restrict__ w1,
    const float* __restrict__ w2, unsigned* __restrict__ wsplit)
{
    if (blockIdx.x < 5120) {
        int idx = blockIdx.x * 256 + threadIdx.x;
        int d = idx & 63;
        int t = idx >> 6;
        int b = t / LSEQ;
        int tt = t % LSEQ;
        float v0 = 0.f, v1 = 0.f;
        if (tt < L0SEQ) {
            v0 = wave[(size_t)(b*2+0)*L0SEQ + tt];
            v1 = wave[(size_t)(b*2+1)*L0SEQ + tt];
        }
        float x = v0 * in_w[d] + v1 * in_w[64 + d] + in_b[d];
        x1[idx] = x;
        x2[idx] = x;
    } else {
        int gid = (blockIdx.x - 5120) * 256 + threadIdx.x;   // < 147456 exactly
        int l = gid / 36864;
        int r = gid % 36864;
        float src; unsigned* dst; int idx; int stride;
        if (r < 4096) {                 // wo: K=64, N=64
            int k = r >> 6, n = r & 63;
            src = wo_w[l*4096 + k*64 + n];
            dst = wsplit + l*8192;
            idx = (((k>>4)*4 + (n>>4))*16 + (n&15))*16 + (k&15);
            stride = 4096;
        } else if (r < 20480) {         // w1: K=64, N=256
            int rr = r - 4096;
            int k = rr >> 8, n = rr & 255;
            src = w1[l*16384 + k*256 + n];
            dst = wsplit + 32768 + l*32768;
            idx = (((k>>4)*16 + (n>>4))*16 + (n&15))*16 + (k&15);
            stride = 16384;
        } else {                        // w2: K=256, N=64
            int rr = r - 20480;
            int k = rr >> 6, n = rr & 63;
            src = w2[l*16384 + k*64 + n];
            dst = wsplit + 163840 + l*32768;
            idx = (((k>>4)*4 + (n>>4))*16 + (n&15))*16 + (k&15);
            stride = 16384;
        }
        unsigned h, m, lo;
        split3(src, h, m, lo);
        dst[idx]          = h | (m<<16);
        dst[idx + stride] = lo | (h<<16);
    }
}

// ---------------- LN + QK/V proj + bucketing + pre-split (R6 passing version) ----------------
__global__ __launch_bounds__(256) void k_qkv(
    const float* __restrict__ x2, const float* __restrict__ g, const float* __restrict__ bta,
    const float* __restrict__ wqk, const float* __restrict__ wv, const float* __restrict__ rot,
    unsigned* __restrict__ qkvs, int* __restrict__ buckets)
{
    __shared__ float xln[16][68];
    __shared__ float qkt[16][68];
    __shared__ float vvt[16][68];
    __shared__ float rots[640];
    int tid = threadIdx.x;
    int b  = blockIdx.x / 80;
    int t0 = (blockIdx.x % 80) * 16;
    int tok = tid >> 4;
    int cg  = tid & 15;
    int c4  = cg * 4;

    for (int i = tid; i < 640; i += 256) rots[i] = rot[i];

    float4 xv4 = *(const float4*)&x2[((size_t)b*LSEQ + t0 + tok)*DM + c4];
    float s = xv4.x + xv4.y + xv4.z + xv4.w;
    float ss = xv4.x*xv4.x + xv4.y*xv4.y + xv4.z*xv4.z + xv4.w*xv4.w;
    s  += __shfl_xor(s,1);  s  += __shfl_xor(s,2);  s  += __shfl_xor(s,4);  s  += __shfl_xor(s,8);
    ss += __shfl_xor(ss,1); ss += __shfl_xor(ss,2); ss += __shfl_xor(ss,4); ss += __shfl_xor(ss,8);
    float m = s * (1.f/64.f);
    float vr = ss * (1.f/64.f) - m*m;
    float rstd = 1.f / sqrtf(vr + 1e-5f);
    {
        float4 g4 = *(const float4*)&g[c4];
        float4 b4 = *(const float4*)&bta[c4];
        float4 o;
        o.x = (xv4.x-m)*rstd*g4.x + b4.x;
        o.y = (xv4.y-m)*rstd*g4.y + b4.y;
        o.z = (xv4.z-m)*rstd*g4.z + b4.z;
        o.w = (xv4.w-m)*rstd*g4.w + b4.w;
        *(float4*)&xln[tok][c4] = o;
    }
    __syncthreads();

    float aq[4] = {0,0,0,0}, av[4] = {0,0,0,0};
    for (int f = 0; f < 64; f++) {
        float4 wq4 = *(const float4*)&wqk[f*64 + c4];
        float4 wv4 = *(const float4*)&wv [f*64 + c4];
        float xv = xln[tok][f];
        aq[0] += xv*wq4.x; aq[1] += xv*wq4.y; aq[2] += xv*wq4.z; aq[3] += xv*wq4.w;
        av[0] += xv*wv4.x; av[1] += xv*wv4.y; av[2] += xv*wv4.z; av[3] += xv*wv4.w;
    }
    *(float4*)&qkt[tok][c4] = *(float4*)aq;
    *(float4*)&vvt[tok][c4] = *(float4*)av;
    __syncthreads();

    int p = tid >> 2;
    int ptok = p >> 2, head = p & 3;
    int sub = tid & 3;
    int e0 = sub * 4;
    int t = t0 + ptok;
    float4 qf4 = *(const float4*)&qkt[ptok][head*16 + e0];
    float nsq = qf4.x*qf4.x + qf4.y*qf4.y + qf4.z*qf4.z + qf4.w*qf4.w;
    nsq += __shfl_xor(nsq,1); nsq += __shfl_xor(nsq,2);
    float inv = 1.f / fmaxf(sqrtf(nsq), 1e-12f);
    float qe[4] = {qf4.x, qf4.y, qf4.z, qf4.w};
    unsigned wq[4], wk[4];
    #pragma unroll
    for (int i=0;i<4;i++){
        float xq = qe[i]*0.25f;
        unsigned qh = rnbf(xq);
        unsigned ql = rnbf(xq - bf2f(qh));
        wq[i] = qh | (ql<<16);
        float xk = qe[i]*inv;
        unsigned kh = rnbf(xk);
        unsigned kl = rnbf(xk - bf2f(kh));
        wk[i] = kh | (kl<<16);
    }
    float4 vf4 = *(const float4*)&vvt[ptok][head*16 + e0];
    unsigned wv1[4];
    wv1[0] = pack_hm_rn(vf4.x); wv1[1] = pack_hm_rn(vf4.y);
    wv1[2] = pack_hm_rn(vf4.z); wv1[3] = pack_hm_rn(vf4.w);
    size_t sb = (((size_t)(b*NHEADS+head))*LSEQ + t)*64;
    *(uint4*)&qkvs[sb + e0]      = *(uint4*)wq;
    *(uint4*)&qkvs[sb + 16 + e0] = *(uint4*)wk;
    *(uint4*)&qkvs[sb + 32 + e0] = *(uint4*)wv1;

    float qf[16];
    {
        float4 a0 = *(const float4*)&qkt[ptok][head*16 + 0];
        float4 a1 = *(const float4*)&qkt[ptok][head*16 + 4];
        float4 a2 = *(const float4*)&qkt[ptok][head*16 + 8];
        float4 a3 = *(const float4*)&qkt[ptok][head*16 + 12];
        qf[0]=a0.x; qf[1]=a0.y; qf[2]=a0.z; qf[3]=a0.w;
        qf[4]=a1.x; qf[5]=a1.y; qf[6]=a1.z; qf[7]=a1.w;
        qf[8]=a2.x; qf[9]=a2.y; qf[10]=a2.z; qf[11]=a2.w;
        qf[12]=a3.x; qf[13]=a3.y; qf[14]=a3.z; qf[15]=a3.w;
    }
    int nh = sub;
    float rv[10];
    #pragma unroll
    for (int i=0;i<10;i++) {
        float acc = 0.f;
        #pragma unroll
        for (int f=0; f<16; f++) acc += qf[f]*rots[(f*NHASH+nh)*10 + i];
        rv[i] = acc;
    }
    float best = rv[0]; int bi = 0;
    #pragma unroll
    for (int i=1;i<10;i++) if (rv[i] > best) { best = rv[i]; bi = i; }
    #pragma unroll
    for (int i=0;i<10;i++) if (-rv[i] > best) { best = -rv[i]; bi = 10+i; }
    buckets[((size_t)(b*NHEADS+head)*NHASH + nh)*LSEQ + t] = bi;
}

// ---------------- counting sort v2 ----------------
__global__ __launch_bounds__(256) void k_sort(
    const int* __restrict__ buckets, int* __restrict__ sorted)
{
    __shared__ unsigned long long masks[20][20];   // [chunk][bucket]
    __shared__ int pre[20][20];                    // prefix over chunks<ch per bucket
    __shared__ int startl[20];
    int tid = threadIdx.x;
    int w = tid >> 6, lane = tid & 63;
    int gidx = blockIdx.x;
    const int* bk = buckets + (size_t)gidx * LSEQ;
    int* dst = sorted + (size_t)gidx * LSEQ;

    int myb[5];
    #pragma unroll
    for (int i = 0; i < 5; i++) {
        int ch = w*5 + i;
        int bv = bk[ch*64 + lane];
        myb[i] = bv;
        #pragma unroll
        for (int b2 = 0; b2 < 20; b2++) {
            unsigned long long m2 = __ballot(bv == b2);
            if (lane == b2) masks[ch][b2] = m2;
        }
    }
    __syncthreads();
    if (tid < 20) {
        int run = 0;
        for (int ch = 0; ch < 20; ch++) {
            pre[ch][tid] = run;
            run += __popcll(masks[ch][tid]);
        }
        startl[tid] = run;          // total count for bucket tid (temp)
    }
    __syncthreads();
    if (tid == 0) {
        int acc = 0;
        for (int b2 = 0; b2 < 20; b2++) { int t = startl[b2]; startl[b2] = acc; acc += t; }
    }
    __syncthreads();
    unsigned long long below = (lane == 63) ? 0x7fffffffffffffffull
                                            : ((1ull << lane) - 1ull);
    #pragma unroll
    for (int i = 0; i < 5; i++) {
        int ch = w*5 + i;
        int bv = myb[i];
        int rank = startl[bv] + pre[ch][bv] + __popcll(masks[ch][bv] & below);
        dst[rank] = ch*64 + lane;
    }
}

// ---------------- chunked attention v15: v14b + early-Q prefetch ----------------
// Q position recomputed from sorted[] at entry (identical element the staging thread
// stores into kposS) so the scattered 16B Q loads issue ~staging-phase earlier.
__global__ __launch_bounds__(256) void k_attn(
    const unsigned* __restrict__ qkvs,
    const int* __restrict__ sorted, float* __restrict__ o_hash, float* __restrict__ slog)
{
    __shared__ __align__(16) unsigned SM[5312];            // 21248 B -> 7 blocks/CU
    unsigned* Va1 = SM;                                    // 2624 u32 [kt8][dh16][key16] strides 328/20
    unsigned* Ka1 = SM + 2624;                             // 2560 u32 [key128][16] stride 20 (phase 1)
    unsigned* Pa1 = SM + 2624;                             // phase 2 alias (P h|m)
    int* kposS = (int*)(SM + 5184);                        // 128 ints

    int tid = threadIdx.x;
    int bh = blockIdx.x & 63;          // XCD swizzle: same bh -> same XCD (64 % 8 == 0)
    int c  = blockIdx.x >> 6;
    int h  = c / NBUK, cc = c % NBUK;
    int cp = (c + NCHUNK - 1) % NCHUNK;
    int hp = cp / NBUK, ccp = cp % NBUK;

    int w = tid >> 6, lane = tid & 63;
    int quad = lane >> 4, col = lane & 15;

    // early Q prefetch: position from global sorted[], load starts before staging
    int qgpos = sorted[((size_t)bh*NHASH + h)*LSEQ + cc*64 + 16*w + col];
    FU4 QA;
    QA.v = *(const uint4*)(qkvs + ((size_t)bh*LSEQ + qgpos)*64 + quad*4);
    frag_ab qA = QA.f;

    int key = tid & 127;
    int pos = (key < 64)
        ? sorted[((size_t)bh*NHASH + h)*LSEQ + cc*64 + key]
        : sorted[((size_t)bh*NHASH + hp)*LSEQ + ccp*64 + (key-64)];
    size_t srow = ((size_t)bh*LSEQ + pos)*64;
    if (tid < 128) {
        kposS[key] = pos;
        const uint4* kr = (const uint4*)(qkvs + srow + 16);
        #pragma unroll
        for (int e4=0; e4<4; e4++)
            *(uint4*)&Ka1[key*20 + e4*4] = kr[e4];
    } else {
        const uint4* v1r = (const uint4*)(qkvs + srow + 32);
        int kt = key >> 4, jl = key & 15;
        int lb = kt*328 + jl;
        #pragma unroll
        for (int e4=0; e4<4; e4++){
            uint4 a = v1r[e4];
            unsigned aa[4] = {a.x,a.y,a.z,a.w};
            #pragma unroll
            for (int i=0;i<4;i++){
                int d = e4*4 + i;
                Va1[lb + d*20] = aa[i];
            }
        }
    }
    __syncthreads();

    frag_c acc[8];
    #pragma unroll
    for (int nt=0; nt<8; nt++){
        FU4 B1, B2;
        B1.v = *(const uint4*)&Ka1[(nt*16+col)*20 + 4*quad];
        B2.v = rot16v(B1.v);
        frag_c a = {0.f,0.f,0.f,0.f};
        a = __builtin_amdgcn_mfma_f32_16x16x32_bf16(qA, B1.f, a, 0, 0, 0);
        a = __builtin_amdgcn_mfma_f32_16x16x32_bf16(qA, B2.f, a, 0, 0, 0);
        acc[nt] = a;
    }
    int qp[4];
    #pragma unroll
    for (int reg=0; reg<4; reg++) qp[reg] = kposS[16*w + quad*4 + reg];

    #pragma unroll
    for (int nt=0; nt<8; nt++) if (nt == w) {
        #pragma unroll
        for (int reg=0; reg<4; reg++)
            acc[nt][reg] = (col == quad*4 + reg) ? -5e4f : acc[nt][reg];
    }
    if (cc == 0) {
        #pragma unroll
        for (int nt=4; nt<8; nt++){
            int kp2 = kposS[nt*16 + col];
            #pragma unroll
            for (int reg=0; reg<4; reg++)
                if (kp2 == qp[reg]) acc[nt][reg] = -5e4f;
        }
    }

    float mx[4] = {-3.4e38f,-3.4e38f,-3.4e38f,-3.4e38f};
    #pragma unroll
    for (int nt=0; nt<8; nt++)
        #pragma unroll
        for (int reg=0; reg<4; reg++) mx[reg] = fmaxf(mx[reg], acc[nt][reg]);
    #pragma unroll
    for (int reg=0; reg<4; reg++){
        float m2 = mx[reg];
        m2 = fmaxf(m2, __shfl_xor(m2, 1)); m2 = fmaxf(m2, __shfl_xor(m2, 2));
        m2 = fmaxf(m2, __shfl_xor(m2, 4)); m2 = fmaxf(m2, __shfl_xor(m2, 8));
        mx[reg] = m2;
    }
    float sm2[4] = {0.f,0.f,0.f,0.f};
    #pragma unroll
    for (int nt=0; nt<8; nt++)
        #pragma unroll
        for (int reg=0; reg<4; reg++){
            float e = __expf(acc[nt][reg] - mx[reg]);
            acc[nt][reg] = e; sm2[reg] += e;
        }
    #pragma unroll
    for (int reg=0; reg<4; reg++){
        float s2 = sm2[reg];
        s2 += __shfl_xor(s2, 1); s2 += __shfl_xor(s2, 2);
        s2 += __shfl_xor(s2, 4); s2 += __shfl_xor(s2, 8);
        sm2[reg] = s2;
    }
    float invs[4];
    #pragma unroll
    for (int reg=0; reg<4; reg++) invs[reg] = __builtin_amdgcn_rcpf(sm2[reg]);
    if (col == 0) {
        #pragma unroll
        for (int reg=0; reg<4; reg++)
            slog[((size_t)bh*NHASH + h)*LSEQ + qp[reg]] = mx[reg] + __logf(sm2[reg]);
    }

    frag_c o = {0.f,0.f,0.f,0.f};
    __syncthreads();   // Ka1 dead -> Pa1 alias safe
    #pragma unroll
    for (int pass=0; pass<4; pass++){
        #pragma unroll
        for (int t2=0; t2<2; t2++){
            int nt = pass*2 + t2;
            #pragma unroll
            for (int reg=0; reg<4; reg++){
                int idx = t2*1280 + (16*w + 4*quad + reg)*20 + col;
                Pa1[idx] = pack_hm(acc[nt][reg]);
            }
        }
        __syncthreads();
        #pragma unroll
        for (int t2=0; t2<2; t2++){
            int ktg = pass*2 + t2;
            FU4 A1, B1, B2;
            int pidx = t2*1280 + (16*w + col)*20 + 4*quad;
            A1.v = *(const uint4*)&Pa1[pidx];
            int vidx = ktg*328 + col*20 + 4*quad;
            B1.v = *(const uint4*)&Va1[vidx];
            B2.v = rot16v(B1.v);
            o = __builtin_amdgcn_mfma_f32_16x16x32_bf16(A1.f, B1.f, o, 0, 0, 0);
            o = __builtin_amdgcn_mfma_f32_16x16x32_bf16(A1.f, B2.f, o, 0, 0, 0);
        }
        if (pass < 3) __syncthreads();
    }
    size_t obase = ((size_t)bh*NHASH + h)*LSEQ;
    #pragma unroll
    for (int reg=0; reg<4; reg++)
        o_hash[(obase + qp[reg])*DHD + col] = o[reg] * invs[reg];
}

// ---------------- fused tail v6 (R6 passing version: red-based w2, A-fragment reuse) ----------------
__global__ __launch_bounds__(256) void k_tail(
    const float* __restrict__ o_hash, const float* __restrict__ slog,
    const unsigned* __restrict__ wo_s, const float* __restrict__ wo_b,
    const float* __restrict__ g2, const float* __restrict__ b2t,
    const unsigned* __restrict__ w1_s, const float* __restrict__ b1,
    const unsigned* __restrict__ w2_s, const float* __restrict__ b2f,
    float* __restrict__ x1, float* __restrict__ x2,
    const float* __restrict__ out_w, const float* __restrict__ out_b,
    float* __restrict__ y, int do_out)
{
    __shared__ unsigned cA1[1024];          // 4 KB: combine h|m; later LN h|m
    __shared__ unsigned short cA2h[1024];   // 2 KB: combine l; later LN l
    __shared__ unsigned gA1[4096];          // 16 KB: gelu h|m per wave; later red
    __shared__ unsigned short gA2h[4096];   // 8 KB: gelu l per wave
    __shared__ float lnS[64], lnQ[64];      // 0.5 KB
    float* red = (float*)gA1;

    int tid = threadIdx.x;
    int b  = blockIdx.x / 80;
    int t0 = (blockIdx.x % 80) * 16;
    int w = tid >> 6, lane = tid & 63;
    int quad = lane >> 4, col = lane & 15;
    int cg = w*16 + col;

    float x1pre[4], x2pre[4];
    #pragma unroll
    for (int reg=0; reg<4; reg++){
        size_t xi = ((size_t)b*LSEQ + t0 + quad*4 + reg)*DM + cg;
        x1pre[reg] = x1[xi];
        x2pre[reg] = x2[xi];
    }
    float wb_pre  = wo_b[cg];
    float gv_pre  = g2[cg];
    float bv_pre  = b2t[cg];
    float bbf_pre = b2f[cg];
    float ow_pre  = out_w[cg];
    float b1v[4];
    #pragma unroll
    for (int ntl=0; ntl<4; ntl++) b1v[ntl] = b1[(w*4 + ntl)*16 + col];

    {
        int tok = tid >> 4;
        int dg  = tid & 15;
        int d0  = dg * 4;
        int kt  = dg >> 2;
        int t = t0 + tok;
        int bh = b*NHEADS + kt;
        float sl[4];
        #pragma unroll
        for (int nh=0; nh<4; nh++) sl[nh] = slog[((size_t)bh*NHASH + nh)*LSEQ + t];
        float mx = fmaxf(fmaxf(sl[0],sl[1]), fmaxf(sl[2],sl[3]));
        float wgt[4]; float wsum = 0.f;
        #pragma unroll
        for (int nh=0; nh<4; nh++){ wgt[nh] = __expf(sl[nh]-mx); wsum += wgt[nh]; }
        float iv = 1.f/wsum;
        float a4[4] = {0.f,0.f,0.f,0.f};
        #pragma unroll
        for (int nh=0; nh<4; nh++){
            float4 oh = *(const float4*)&o_hash[(((size_t)bh*NHASH + nh)*LSEQ + t)*DHD + (d0 & 15)];
            float wn = wgt[nh]*iv;
            a4[0] += wn*oh.x; a4[1] += wn*oh.y; a4[2] += wn*oh.z; a4[3] += wn*oh.w;
        }
        int sw = (tok & 7) << 2;
        unsigned cw1[4], lw[4];
        #pragma unroll
        for (int i=0;i<4;i++) split_hml(a4[i], cw1[i], lw[i]);
        *(uint4*)&cA1[tok*64 + (d0 ^ sw)] = *(uint4*)cw1;
        uint2 lp;
        lp.x = lw[0] | (lw[1]<<16);
        lp.y = lw[2] | (lw[3]<<16);
        *(uint2*)&cA2h[tok*64 + (d0 ^ sw)] = lp;
    }
    __syncthreads();
    FU4 aA1[4], aA2[4];
    {
        int sw = (col & 7) << 2;
        #pragma unroll
        for (int kt=0; kt<4; kt++){
            int word = (kt*16 + quad*4) ^ sw;
            aA1[kt].v = *(const uint4*)&cA1[col*64 + word];
            uint2 zl = *(const uint2*)&cA2h[col*64 + word];
            aA2[kt].v.x = __builtin_amdgcn_perm(zl.x, aA1[kt].v.x, 0x05040100u);
            aA2[kt].v.y = __builtin_amdgcn_perm(zl.x, aA1[kt].v.y, 0x07060100u);
            aA2[kt].v.z = __builtin_amdgcn_perm(zl.y, aA1[kt].v.z, 0x05040100u);
            aA2[kt].v.w = __builtin_amdgcn_perm(zl.y, aA1[kt].v.w, 0x07060100u);
        }
    }

    frag_c awo = {0.f,0.f,0.f,0.f};
    #pragma unroll
    for (int kt=0; kt<4; kt++){
        FU4 B1, B2, B3;
        int bidx = ((kt*4 + w)*16 + col)*16 + quad*4;
        B1.v = *(const uint4*)&wo_s[bidx];
        B2.v = rot16v(B1.v);
        B3.v = *(const uint4*)&wo_s[bidx + 4096];
        awo = __builtin_amdgcn_mfma_f32_16x16x32_bf16(aA1[kt].f, B1.f, awo, 0, 0, 0);
        awo = __builtin_amdgcn_mfma_f32_16x16x32_bf16(aA1[kt].f, B2.f, awo, 0, 0, 0);
        awo = __builtin_amdgcn_mfma_f32_16x16x32_bf16(aA2[kt].f, B3.f, awo, 0, 0, 0);
    }
    float x1n[4];
    float s1[4], s2[4];
    {
        #pragma unroll
        for (int reg=0; reg<4; reg++){
            int rg = t0 + quad*4 + reg;
            size_t xi = ((size_t)b*LSEQ + rg)*DM + cg;
            float xv = x1pre[reg] + awo[reg] + wb_pre;
            x1[xi] = xv;
            x1n[reg] = xv;
            s1[reg] = xv; s2[reg] = xv*xv;
        }
    }
    #pragma unroll
    for (int reg=0; reg<4; reg++){
        float a = s1[reg], q = s2[reg];
        a += __shfl_xor(a,1); a += __shfl_xor(a,2); a += __shfl_xor(a,4); a += __shfl_xor(a,8);
        q += __shfl_xor(q,1); q += __shfl_xor(q,2); q += __shfl_xor(q,4); q += __shfl_xor(q,8);
        s1[reg] = a; s2[reg] = q;
    }
    if (col == 0) {
        #pragma unroll
        for (int reg=0; reg<4; reg++){
            lnS[w*16 + quad*4 + reg] = s1[reg];
            lnQ[w*16 + quad*4 + reg] = s2[reg];
        }
    }
    __syncthreads();   // also orders aA reads (above) before LN writes (below) into cA
    float mean[4], rstd[4];
    #pragma unroll
    for (int reg=0; reg<4; reg++){
        int tok = quad*4 + reg;
        float a = lnS[tok] + lnS[16+tok] + lnS[32+tok] + lnS[48+tok];
        float q = lnQ[tok] + lnQ[16+tok] + lnQ[32+tok] + lnQ[48+tok];
        mean[reg] = a*(1.f/64.f);
        float var = q*(1.f/64.f) - mean[reg]*mean[reg];
        rstd[reg] = 1.f/sqrtf(var + 1e-5f);
    }
    {
        #pragma unroll
        for (int reg=0; reg<4; reg++){
            int row = quad*4 + reg;
            float xv = (x1n[reg]-mean[reg])*rstd[reg]*gv_pre + bv_pre;
            unsigned hm_, l_;
            split_hml(xv, hm_, l_);
            int word = cg ^ ((row & 7) << 2);
            cA1[row*64 + word] = hm_;
            cA2h[row*64 + word] = (unsigned short)l_;
        }
    }
    __syncthreads();
    FU4 xa1[4], xa2[4];
    {
        int sw = (col & 7) << 2;
        #pragma unroll
        for (int kt=0; kt<4; kt++){
            int word = (kt*16 + quad*4) ^ sw;
            xa1[kt].v = *(const uint4*)&cA1[col*64 + word];
            uint2 zl = *(const uint2*)&cA2h[col*64 + word];
            xa2[kt].v.x = __builtin_amdgcn_perm(zl.x, xa1[kt].v.x, 0x05040100u);
            xa2[kt].v.y = __builtin_amdgcn_perm(zl.x, xa1[kt].v.y, 0x07060100u);
            xa2[kt].v.z = __builtin_amdgcn_perm(zl.y, xa1[kt].v.z, 0x05040100u);
            xa2[kt].v.w = __builtin_amdgcn_perm(zl.y, xa1[kt].v.w, 0x07060100u);
        }
    }

    unsigned* myg1 = gA1 + w*1024;
    unsigned short* myg2h = gA2h + w*1024;
    #pragma unroll
    for (int ntl=0; ntl<4; ntl++){
        int nt = w*4 + ntl;
        frag_c a = {0.f,0.f,0.f,0.f};
        #pragma unroll
        for (int kt=0; kt<4; kt++){
            FU4 B1, B2, B3;
            int bidx = ((kt*16 + nt)*16 + col)*16 + quad*4;
            B1.v = *(const uint4*)&w1_s[bidx];
            B2.v = rot16v(B1.v);
            B3.v = *(const uint4*)&w1_s[bidx + 16384];
            a = __builtin_amdgcn_mfma_f32_16x16x32_bf16(xa1[kt].f, B1.f, a, 0, 0, 0);
            a = __builtin_amdgcn_mfma_f32_16x16x32_bf16(xa1[kt].f, B2.f, a, 0, 0, 0);
            a = __builtin_amdgcn_mfma_f32_16x16x32_bf16(xa2[kt].f, B3.f, a, 0, 0, 0);
        }
        float bb = b1v[ntl];
        #pragma unroll
        for (int reg=0; reg<4; reg++){
            float xx = a[reg] + bb;
            float ge = gelu_fast(xx);
            unsigned hm_, l_;
            split_hml(ge, hm_, l_);
            int row = quad*4 + reg;
            int word = (ntl*16 + col) ^ ((row & 7) << 2);
            myg1[row*64 + word] = hm_;
            myg2h[row*64 + word] = (unsigned short)l_;
        }
    }
    frag_c aw2[4] = {{0,0,0,0},{0,0,0,0},{0,0,0,0},{0,0,0,0}};
    {
        int sw = (col & 7) << 2;
        #pragma unroll
        for (int kt2=0; kt2<4; kt2++){
            FU4 A1, A2;
            int word = (kt2*16 + quad*4) ^ sw;
            A1.v = *(const uint4*)&myg1[col*64 + word];
            uint2 zl = *(const uint2*)&myg2h[col*64 + word];
            A2.v.x = __builtin_amdgcn_perm(zl.x, A1.v.x, 0x05040100u);
            A2.v.y = __builtin_amdgcn_perm(zl.x, A1.v.y, 0x07060100u);
            A2.v.z = __builtin_amdgcn_perm(zl.y, A1.v.z, 0x05040100u);
            A2.v.w = __builtin_amdgcn_perm(zl.y, A1.v.w, 0x07060100u);
            int kg = w*4 + kt2;
            #pragma unroll
            for (int nt2=0; nt2<4; nt2++){
                FU4 B1, B2, B3;
                int bidx = ((kg*4 + nt2)*16 + col)*16 + quad*4;
                B1.v = *(const uint4*)&w2_s[bidx];
                B2.v = rot16v(B1.v);
                B3.v = *(const uint4*)&w2_s[bidx + 16384];
                aw2[nt2] = __builtin_amdgcn_mfma_f32_16x16x32_bf16(A1.f, B1.f, aw2[nt2], 0, 0, 0);
                aw2[nt2] = __builtin_amdgcn_mfma_f32_16x16x32_bf16(A1.f, B2.f, aw2[nt2], 0, 0, 0);
                aw2[nt2] = __builtin_amdgcn_mfma_f32_16x16x32_bf16(A2.f, B3.f, aw2[nt2], 0, 0, 0);
            }
        }
    }
    __syncthreads();
    #pragma unroll
    for (int nt2=0; nt2<4; nt2++)
        #pragma unroll
        for (int reg=0; reg<4; reg++)
            red[((w*4 + nt2)*4 + reg)*64 + lane] = aw2[nt2][reg];
    __syncthreads();
    float x2f[4];
    {
        #pragma unroll
        for (int reg=0; reg<4; reg++){
            float v = red[((0*4 + w)*4 + reg)*64 + lane]
                    + red[((1*4 + w)*4 + reg)*64 + lane]
                    + red[((2*4 + w)*4 + reg)*64 + lane]
                    + red[((3*4 + w)*4 + reg)*64 + lane];
            int rg = t0 + quad*4 + reg;
            size_t xi = ((size_t)b*LSEQ + rg)*DM + cg;
            float nv = x2pre[reg] + v + bbf_pre;
            x2[xi] = nv;
            x2f[reg] = nv;
        }
    }
    if (do_out) {
        float part[4];
        #pragma unroll
        for (int reg=0; reg<4; reg++){
            float p = (x1n[reg] + x2f[reg]) * 0.5f * ow_pre;
            p += __shfl_xor(p,1); p += __shfl_xor(p,2); p += __shfl_xor(p,4); p += __shfl_xor(p,8);
            part[reg] = p;
        }
        __syncthreads();
        if (col == 0) {
            #pragma unroll
            for (int reg=0; reg<4; reg++)
                lnS[w*16 + quad*4 + reg] = part[reg];
        }
        __syncthreads();
        if (tid < 16) {
            int t = t0 + tid;
            if (t < L0SEQ) {
                float v2 = lnS[tid] + lnS[16+tid] + lnS[32+tid] + lnS[48+tid];
                y[(size_t)b*L0SEQ + t] = v2 + out_b[0];
            }
        }
    }
}

extern "C" void kernel_launch(void* const* d_in, const int* in_sizes, int n_in,
                              void* d_out, int out_size, void* d_ws, size_t ws_size,
                              hipStream_t stream)
{
    const float* wave  = (const float*)d_in[0];
    const float* in_w  = (const float*)d_in[1];
    const float* in_b  = (const float*)d_in[2];
    const float* ln1_g = (const float*)d_in[3];
    const float* ln1_b = (const float*)d_in[4];
    const float* wqk   = (const float*)d_in[5];
    const float* wv    = (const float*)d_in[6];
    const float* wo_w  = (const float*)d_in[7];
    const float* wo_b  = (const float*)d_in[8];
    const float* rot   = (const float*)d_in[9];
    const float* ln2_g = (const float*)d_in[10];
    const float* ln2_b = (const float*)d_in[11];
    const float* w1    = (const float*)d_in[12];
    const float* b1    = (const float*)d_in[13];
    const float* w2    = (const float*)d_in[14];
    const float* b2    = (const float*)d_in[15];
    const float* out_w = (const float*)d_in[16];
    const float* out_b = (const float*)d_in[17];
    float* y = (float*)d_out;

    float* ws = (float*)d_ws;
    float* x1      = ws;                       // XSZ f32
    float* x2      = x1 + XSZ;                 // XSZ f32
    unsigned* qkvs = (unsigned*)(x2 + XSZ);    // 4*QKSZ u32 (interleaved)
    float* o_hash  = (float*)(qkvs + 4*QKSZ);  // OHSZ f32
    float* slogb   = o_hash + OHSZ;            // SLSZ f32
    int* buckets   = (int*)(slogb + SLSZ);     // SLSZ int
    int* sorted    = buckets + SLSZ;           // SLSZ int
    unsigned* wsplit = (unsigned*)(sorted + SLSZ); // 294912 u32

    k_init<<<5696, 256, 0, stream>>>(wave, in_w, in_b, x1, x2, wo_w, w1, w2, wsplit);
    for (int layer = 0; layer < 4; layer++) {
        k_qkv<<<NBATCH*80, 256, 0, stream>>>(x2, ln1_g + layer*64, ln1_b + layer*64,
                                       wqk + layer*4096, wv + layer*4096, rot + layer*640,
                                       qkvs, buckets);
        k_sort<<<256, 256, 0, stream>>>(buckets, sorted);
        k_attn<<<NBH*NCHUNK, 256, 0, stream>>>(qkvs, sorted, o_hash, slogb);
        k_tail<<<NBATCH*LSEQ/16, 256, 0, stream>>>(o_hash, slogb,
                                        wsplit + layer*8192, wo_b + layer*64,
                                        ln2_g + layer*64, ln2_b + layer*64,
                                        wsplit + 32768 + layer*32768, b1 + layer*256,
                                        wsplit + 163840 + layer*32768, b2 + layer*64,
                                        x1, x2,
                                        out_w, out_b, y, (layer == 3) ? 1 : 0);
    }
}

// Round 11
// 469.922 us; speedup vs baseline: 1.0292x; 1.0155x over previous
//
#include <hip/hip_runtime.h>
#include <math.h>

#define LSEQ 1280
#define L0SEQ 1250
#define DM 64
#define NHEADS 4
#define DHD 16
#define NHASH 4
#define NBUK 20
#define NCHUNK 80
#define FFD 256
#define NBATCH 16
#define NBH 64

#define XSZ (NBATCH*LSEQ*DM)        // 1310720
#define QKSZ (NBH*LSEQ*DHD)         // 1310720
#define OHSZ (NBH*NHASH*LSEQ*DHD)   // 5242880
#define SLSZ (NBH*NHASH*LSEQ)       // 327680

typedef __attribute__((ext_vector_type(8))) short frag_ab;   // 8 bf16
typedef __attribute__((ext_vector_type(4))) float frag_c;    // 4 fp32

union FU4 { uint4 v; frag_ab f; };

__device__ __forceinline__ unsigned rnbf(float x){
    unsigned b = __float_as_uint(x);
    return (b + 0x7fffu + ((b >> 16) & 1u)) >> 16;
}
__device__ __forceinline__ float bf2f(unsigned h){ return __uint_as_float(h << 16); }
__device__ __forceinline__ unsigned rot16(unsigned x){ return (x >> 16) | (x << 16); }
__device__ __forceinline__ uint4 rot16v(uint4 a){
    uint4 r; r.x=rot16(a.x); r.y=rot16(a.y); r.z=rot16(a.z); r.w=rot16(a.w); return r;
}

// exact triple split (truncation): x = h + m + l
__device__ __forceinline__ void split3(float x, unsigned& h, unsigned& m, unsigned& l){
    unsigned bx = __float_as_uint(x);
    h = bx >> 16;
    float r = x - __uint_as_float(bx & 0xffff0000u);
    unsigned br = __float_as_uint(r);
    m = br >> 16;
    float r2 = r - __uint_as_float(br & 0xffff0000u);
    l = __float_as_uint(r2) >> 16;
}

// 2-limb split packed (h | m<<16) in one v_perm (truncation)
__device__ __forceinline__ unsigned pack_hm(float x){
    unsigned bx = __float_as_uint(x);
    float r = x - __uint_as_float(bx & 0xffff0000u);
    return __builtin_amdgcn_perm(__float_as_uint(r), bx, 0x07060302u);
}

// 2-limb ROUNDED split (residual <= 2^-18 |x|)
__device__ __forceinline__ unsigned pack_hm_rn(float x){
    unsigned h = rnbf(x);
    unsigned m = rnbf(x - bf2f(h));
    return h | (m << 16);
}

// 3-limb split: hm = h|(m<<16) packed via perm; l as bare u16
__device__ __forceinline__ void split_hml(float x, unsigned& hm, unsigned& l){
    unsigned bx = __float_as_uint(x);
    float r = x - __uint_as_float(bx & 0xffff0000u);
    unsigned br = __float_as_uint(r);
    hm = __builtin_amdgcn_perm(br, bx, 0x07060302u);
    float r2 = r - __uint_as_float(br & 0xffff0000u);
    l = __float_as_uint(r2) >> 16;
}

// gelu with A&S 7.1.26 erf (|err| <= 1.5e-7)
__device__ __forceinline__ float gelu_fast(float x){
    float ax = fabsf(x) * 0.70710678118654752f;
    float t = __builtin_amdgcn_rcpf(1.f + 0.3275911f*ax);
    float poly = ((((1.061405429f*t - 1.453152027f)*t + 1.421413741f)*t
                   - 0.284496736f)*t + 0.254829592f)*t;
    float e = 1.f - poly * __expf(-ax*ax);
    float er = __uint_as_float((__float_as_uint(e) & 0x7fffffffu) |
                               (__float_as_uint(x) & 0x80000000u));
    return 0.5f*x*(1.f + er);
}

// ---------------- init: embed (blocks 0..5119) + weight pre-split (blocks 5120..5695) ----------------
__global__ __launch_bounds__(256) void k_init(
    const float* __restrict__ wave, const float* __restrict__ in_w, const float* __restrict__ in_b,
    float* __restrict__ x1, float* __restrict__ x2,
    const float* __restrict__ wo_w, const float* __restrict__ w1,
    const float* __restrict__ w2, unsigned* __restrict__ wsplit)
{
    if (blockIdx.x < 5120) {
        int idx = blockIdx.x * 256 + threadIdx.x;
        int d = idx & 63;
        int t = idx >> 6;
        int b = t / LSEQ;
        int tt = t % LSEQ;
        float v0 = 0.f, v1 = 0.f;
        if (tt < L0SEQ) {
            v0 = wave[(size_t)(b*2+0)*L0SEQ + tt];
            v1 = wave[(size_t)(b*2+1)*L0SEQ + tt];
        }
        float x = v0 * in_w[d] + v1 * in_w[64 + d] + in_b[d];
        x1[idx] = x;
        x2[idx] = x;
    } else {
        int gid = (blockIdx.x - 5120) * 256 + threadIdx.x;   // < 147456 exactly
        int l = gid / 36864;
        int r = gid % 36864;
        float src; unsigned* dst; int idx; int stride;
        if (r < 4096) {                 // wo: K=64, N=64
            int k = r >> 6, n = r & 63;
            src = wo_w[l*4096 + k*64 + n];
            dst = wsplit + l*8192;
            idx = (((k>>4)*4 + (n>>4))*16 + (n&15))*16 + (k&15);
            stride = 4096;
        } else if (r < 20480) {         // w1: K=64, N=256
            int rr = r - 4096;
            int k = rr >> 8, n = rr & 255;
            src = w1[l*16384 + k*256 + n];
            dst = wsplit + 32768 + l*32768;
            idx = (((k>>4)*16 + (n>>4))*16 + (n&15))*16 + (k&15);
            stride = 16384;
        } else {                        // w2: K=256, N=64
            int rr = r - 20480;
            int k = rr >> 6, n = rr & 63;
            src = w2[l*16384 + k*64 + n];
            dst = wsplit + 163840 + l*32768;
            idx = (((k>>4)*4 + (n>>4))*16 + (n&15))*16 + (k&15);
            stride = 16384;
        }
        unsigned h, m, lo;
        split3(src, h, m, lo);
        dst[idx]          = h | (m<<16);
        dst[idx + stride] = lo | (h<<16);
    }
}

// ---------------- LN + QK/V proj + bucketing + pre-split (R6 passing version) ----------------
__global__ __launch_bounds__(256) void k_qkv(
    const float* __restrict__ x2, const float* __restrict__ g, const float* __restrict__ bta,
    const float* __restrict__ wqk, const float* __restrict__ wv, const float* __restrict__ rot,
    unsigned* __restrict__ qkvs, int* __restrict__ buckets)
{
    __shared__ float xln[16][68];
    __shared__ float qkt[16][68];
    __shared__ float vvt[16][68];
    __shared__ float rots[640];
    int tid = threadIdx.x;
    int b  = blockIdx.x / 80;
    int t0 = (blockIdx.x % 80) * 16;
    int tok = tid >> 4;
    int cg  = tid & 15;
    int c4  = cg * 4;

    for (int i = tid; i < 640; i += 256) rots[i] = rot[i];

    float4 xv4 = *(const float4*)&x2[((size_t)b*LSEQ + t0 + tok)*DM + c4];
    float s = xv4.x + xv4.y + xv4.z + xv4.w;
    float ss = xv4.x*xv4.x + xv4.y*xv4.y + xv4.z*xv4.z + xv4.w*xv4.w;
    s  += __shfl_xor(s,1);  s  += __shfl_xor(s,2);  s  += __shfl_xor(s,4);  s  += __shfl_xor(s,8);
    ss += __shfl_xor(ss,1); ss += __shfl_xor(ss,2); ss += __shfl_xor(ss,4); ss += __shfl_xor(ss,8);
    float m = s * (1.f/64.f);
    float vr = ss * (1.f/64.f) - m*m;
    float rstd = 1.f / sqrtf(vr + 1e-5f);
    {
        float4 g4 = *(const float4*)&g[c4];
        float4 b4 = *(const float4*)&bta[c4];
        float4 o;
        o.x = (xv4.x-m)*rstd*g4.x + b4.x;
        o.y = (xv4.y-m)*rstd*g4.y + b4.y;
        o.z = (xv4.z-m)*rstd*g4.z + b4.z;
        o.w = (xv4.w-m)*rstd*g4.w + b4.w;
        *(float4*)&xln[tok][c4] = o;
    }
    __syncthreads();

    float aq[4] = {0,0,0,0}, av[4] = {0,0,0,0};
    for (int f = 0; f < 64; f++) {
        float4 wq4 = *(const float4*)&wqk[f*64 + c4];
        float4 wv4 = *(const float4*)&wv [f*64 + c4];
        float xv = xln[tok][f];
        aq[0] += xv*wq4.x; aq[1] += xv*wq4.y; aq[2] += xv*wq4.z; aq[3] += xv*wq4.w;
        av[0] += xv*wv4.x; av[1] += xv*wv4.y; av[2] += xv*wv4.z; av[3] += xv*wv4.w;
    }
    *(float4*)&qkt[tok][c4] = *(float4*)aq;
    *(float4*)&vvt[tok][c4] = *(float4*)av;
    __syncthreads();

    int p = tid >> 2;
    int ptok = p >> 2, head = p & 3;
    int sub = tid & 3;
    int e0 = sub * 4;
    int t = t0 + ptok;
    float4 qf4 = *(const float4*)&qkt[ptok][head*16 + e0];
    float nsq = qf4.x*qf4.x + qf4.y*qf4.y + qf4.z*qf4.z + qf4.w*qf4.w;
    nsq += __shfl_xor(nsq,1); nsq += __shfl_xor(nsq,2);
    float inv = 1.f / fmaxf(sqrtf(nsq), 1e-12f);
    float qe[4] = {qf4.x, qf4.y, qf4.z, qf4.w};
    unsigned wq[4], wk[4];
    #pragma unroll
    for (int i=0;i<4;i++){
        float xq = qe[i]*0.25f;
        unsigned qh = rnbf(xq);
        unsigned ql = rnbf(xq - bf2f(qh));
        wq[i] = qh | (ql<<16);
        float xk = qe[i]*inv;
        unsigned kh = rnbf(xk);
        unsigned kl = rnbf(xk - bf2f(kh));
        wk[i] = kh | (kl<<16);
    }
    float4 vf4 = *(const float4*)&vvt[ptok][head*16 + e0];
    unsigned wv1[4];
    wv1[0] = pack_hm_rn(vf4.x); wv1[1] = pack_hm_rn(vf4.y);
    wv1[2] = pack_hm_rn(vf4.z); wv1[3] = pack_hm_rn(vf4.w);
    size_t sb = (((size_t)(b*NHEADS+head))*LSEQ + t)*64;
    *(uint4*)&qkvs[sb + e0]      = *(uint4*)wq;
    *(uint4*)&qkvs[sb + 16 + e0] = *(uint4*)wk;
    *(uint4*)&qkvs[sb + 32 + e0] = *(uint4*)wv1;

    float qf[16];
    {
        float4 a0 = *(const float4*)&qkt[ptok][head*16 + 0];
        float4 a1 = *(const float4*)&qkt[ptok][head*16 + 4];
        float4 a2 = *(const float4*)&qkt[ptok][head*16 + 8];
        float4 a3 = *(const float4*)&qkt[ptok][head*16 + 12];
        qf[0]=a0.x; qf[1]=a0.y; qf[2]=a0.z; qf[3]=a0.w;
        qf[4]=a1.x; qf[5]=a1.y; qf[6]=a1.z; qf[7]=a1.w;
        qf[8]=a2.x; qf[9]=a2.y; qf[10]=a2.z; qf[11]=a2.w;
        qf[12]=a3.x; qf[13]=a3.y; qf[14]=a3.z; qf[15]=a3.w;
    }
    int nh = sub;
    float rv[10];
    #pragma unroll
    for (int i=0;i<10;i++) {
        float acc = 0.f;
        #pragma unroll
        for (int f=0; f<16; f++) acc += qf[f]*rots[(f*NHASH+nh)*10 + i];
        rv[i] = acc;
    }
    float best = rv[0]; int bi = 0;
    #pragma unroll
    for (int i=1;i<10;i++) if (rv[i] > best) { best = rv[i]; bi = i; }
    #pragma unroll
    for (int i=0;i<10;i++) if (-rv[i] > best) { best = -rv[i]; bi = 10+i; }
    buckets[((size_t)(b*NHEADS+head)*NHASH + nh)*LSEQ + t] = bi;
}

// ---------------- counting sort v2 ----------------
__global__ __launch_bounds__(256) void k_sort(
    const int* __restrict__ buckets, int* __restrict__ sorted)
{
    __shared__ unsigned long long masks[20][20];   // [chunk][bucket]
    __shared__ int pre[20][20];                    // prefix over chunks<ch per bucket
    __shared__ int startl[20];
    int tid = threadIdx.x;
    int w = tid >> 6, lane = tid & 63;
    int gidx = blockIdx.x;
    const int* bk = buckets + (size_t)gidx * LSEQ;
    int* dst = sorted + (size_t)gidx * LSEQ;

    int myb[5];
    #pragma unroll
    for (int i = 0; i < 5; i++) {
        int ch = w*5 + i;
        int bv = bk[ch*64 + lane];
        myb[i] = bv;
        #pragma unroll
        for (int b2 = 0; b2 < 20; b2++) {
            unsigned long long m2 = __ballot(bv == b2);
            if (lane == b2) masks[ch][b2] = m2;
        }
    }
    __syncthreads();
    if (tid < 20) {
        int run = 0;
        for (int ch = 0; ch < 20; ch++) {
            pre[ch][tid] = run;
            run += __popcll(masks[ch][tid]);
        }
        startl[tid] = run;          // total count for bucket tid (temp)
    }
    __syncthreads();
    if (tid == 0) {
        int acc = 0;
        for (int b2 = 0; b2 < 20; b2++) { int t = startl[b2]; startl[b2] = acc; acc += t; }
    }
    __syncthreads();
    unsigned long long below = (lane == 63) ? 0x7fffffffffffffffull
                                            : ((1ull << lane) - 1ull);
    #pragma unroll
    for (int i = 0; i < 5; i++) {
        int ch = w*5 + i;
        int bv = myb[i];
        int rank = startl[bv] + pre[ch][bv] + __popcll(masks[ch][bv] & below);
        dst[rank] = ch*64 + lane;
    }
}

// ---------------- chunked attention v16: R6 flow, intra-PV barriers removed ----------------
// P staging (Pa1) write rows 16w+4q+reg and read rows 16w+col are BOTH confined to the
// wave's private rows 16w..16w+15; same-wave LDS RAW is ordered by the compiler's
// lgkmcnt waits, so only the initial cross-wave alias barrier (Ka1 -> Pa1) is kept.
__global__ __launch_bounds__(256) void k_attn(
    const unsigned* __restrict__ qkvs,
    const int* __restrict__ sorted, float* __restrict__ o_hash, float* __restrict__ slog)
{
    __shared__ __align__(16) unsigned SM[5312];            // 21248 B -> 7 blocks/CU
    unsigned* Va1 = SM;                                    // 2624 u32 [kt8][dh16][key16] strides 328/20
    unsigned* Ka1 = SM + 2624;                             // 2560 u32 [key128][16] stride 20 (phase 1)
    unsigned* Pa1 = SM + 2624;                             // phase 2 alias (P h|m)
    int* kposS = (int*)(SM + 5184);                        // 128 ints

    int tid = threadIdx.x;
    int bh = blockIdx.x & 63;          // XCD swizzle: same bh -> same XCD (64 % 8 == 0)
    int c  = blockIdx.x >> 6;
    int h  = c / NBUK, cc = c % NBUK;
    int cp = (c + NCHUNK - 1) % NCHUNK;
    int hp = cp / NBUK, ccp = cp % NBUK;

    int key = tid & 127;
    int pos = (key < 64)
        ? sorted[((size_t)bh*NHASH + h)*LSEQ + cc*64 + key]
        : sorted[((size_t)bh*NHASH + hp)*LSEQ + ccp*64 + (key-64)];
    size_t srow = ((size_t)bh*LSEQ + pos)*64;
    if (tid < 128) {
        kposS[key] = pos;
        const uint4* kr = (const uint4*)(qkvs + srow + 16);
        #pragma unroll
        for (int e4=0; e4<4; e4++)
            *(uint4*)&Ka1[key*20 + e4*4] = kr[e4];
    } else {
        const uint4* v1r = (const uint4*)(qkvs + srow + 32);
        int kt = key >> 4, jl = key & 15;
        int lb = kt*328 + jl;
        #pragma unroll
        for (int e4=0; e4<4; e4++){
            uint4 a = v1r[e4];
            unsigned aa[4] = {a.x,a.y,a.z,a.w};
            #pragma unroll
            for (int i=0;i<4;i++){
                int d = e4*4 + i;
                Va1[lb + d*20] = aa[i];
            }
        }
    }
    __syncthreads();

    int w = tid >> 6, lane = tid & 63;
    int quad = lane >> 4, col = lane & 15;

    int qgpos = kposS[16*w + col];
    FU4 QA;
    QA.v = *(const uint4*)(qkvs + ((size_t)bh*LSEQ + qgpos)*64 + quad*4);
    frag_ab qA = QA.f;

    frag_c acc[8];
    #pragma unroll
    for (int nt=0; nt<8; nt++){
        FU4 B1, B2;
        B1.v = *(const uint4*)&Ka1[(nt*16+col)*20 + 4*quad];
        B2.v = rot16v(B1.v);
        frag_c a = {0.f,0.f,0.f,0.f};
        a = __builtin_amdgcn_mfma_f32_16x16x32_bf16(qA, B1.f, a, 0, 0, 0);
        a = __builtin_amdgcn_mfma_f32_16x16x32_bf16(qA, B2.f, a, 0, 0, 0);
        acc[nt] = a;
    }
    int qp[4];
    #pragma unroll
    for (int reg=0; reg<4; reg++) qp[reg] = kposS[16*w + quad*4 + reg];

    #pragma unroll
    for (int nt=0; nt<8; nt++) if (nt == w) {
        #pragma unroll
        for (int reg=0; reg<4; reg++)
            acc[nt][reg] = (col == quad*4 + reg) ? -5e4f : acc[nt][reg];
    }
    if (cc == 0) {
        #pragma unroll
        for (int nt=4; nt<8; nt++){
            int kp2 = kposS[nt*16 + col];
            #pragma unroll
            for (int reg=0; reg<4; reg++)
                if (kp2 == qp[reg]) acc[nt][reg] = -5e4f;
        }
    }

    float mx[4] = {-3.4e38f,-3.4e38f,-3.4e38f,-3.4e38f};
    #pragma unroll
    for (int nt=0; nt<8; nt++)
        #pragma unroll
        for (int reg=0; reg<4; reg++) mx[reg] = fmaxf(mx[reg], acc[nt][reg]);
    #pragma unroll
    for (int reg=0; reg<4; reg++){
        float m2 = mx[reg];
        m2 = fmaxf(m2, __shfl_xor(m2, 1)); m2 = fmaxf(m2, __shfl_xor(m2, 2));
        m2 = fmaxf(m2, __shfl_xor(m2, 4)); m2 = fmaxf(m2, __shfl_xor(m2, 8));
        mx[reg] = m2;
    }
    float sm2[4] = {0.f,0.f,0.f,0.f};
    #pragma unroll
    for (int nt=0; nt<8; nt++)
        #pragma unroll
        for (int reg=0; reg<4; reg++){
            float e = __expf(acc[nt][reg] - mx[reg]);
            acc[nt][reg] = e; sm2[reg] += e;
        }
    #pragma unroll
    for (int reg=0; reg<4; reg++){
        float s2 = sm2[reg];
        s2 += __shfl_xor(s2, 1); s2 += __shfl_xor(s2, 2);
        s2 += __shfl_xor(s2, 4); s2 += __shfl_xor(s2, 8);
        sm2[reg] = s2;
    }
    float invs[4];
    #pragma unroll
    for (int reg=0; reg<4; reg++) invs[reg] = __builtin_amdgcn_rcpf(sm2[reg]);
    if (col == 0) {
        #pragma unroll
        for (int reg=0; reg<4; reg++)
            slog[((size_t)bh*NHASH + h)*LSEQ + qp[reg]] = mx[reg] + __logf(sm2[reg]);
    }

    frag_c o = {0.f,0.f,0.f,0.f};
    __syncthreads();   // cross-wave: all waves done reading Ka1 before Pa1 alias writes
    #pragma unroll
    for (int pass=0; pass<4; pass++){
        #pragma unroll
        for (int t2=0; t2<2; t2++){
            int nt = pass*2 + t2;
            #pragma unroll
            for (int reg=0; reg<4; reg++){
                int idx = t2*1280 + (16*w + 4*quad + reg)*20 + col;
                Pa1[idx] = pack_hm(acc[nt][reg]);
            }
        }
        // no barrier: same-wave LDS RAW (rows 16w..16w+15), lgkmcnt-ordered
        #pragma unroll
        for (int t2=0; t2<2; t2++){
            int ktg = pass*2 + t2;
            FU4 A1, B1, B2;
            int pidx = t2*1280 + (16*w + col)*20 + 4*quad;
            A1.v = *(const uint4*)&Pa1[pidx];
            int vidx = ktg*328 + col*20 + 4*quad;
            B1.v = *(const uint4*)&Va1[vidx];
            B2.v = rot16v(B1.v);
            o = __builtin_amdgcn_mfma_f32_16x16x32_bf16(A1.f, B1.f, o, 0, 0, 0);
            o = __builtin_amdgcn_mfma_f32_16x16x32_bf16(A1.f, B2.f, o, 0, 0, 0);
        }
        // no barrier: next pass overwrites the same wave's own region
    }
    size_t obase = ((size_t)bh*NHASH + h)*LSEQ;
    #pragma unroll
    for (int reg=0; reg<4; reg++)
        o_hash[(obase + qp[reg])*DHD + col] = o[reg] * invs[reg];
}

// ---------------- fused tail v10: R6 version minus the unnecessary pre-red barrier ----------------
// (red region of wave w aliases only wave w's own myg1 region -> same-wave ordering suffices)
__global__ __launch_bounds__(256) void k_tail(
    const float* __restrict__ o_hash, const float* __restrict__ slog,
    const unsigned* __restrict__ wo_s, const float* __restrict__ wo_b,
    const float* __restrict__ g2, const float* __restrict__ b2t,
    const unsigned* __restrict__ w1_s, const float* __restrict__ b1,
    const unsigned* __restrict__ w2_s, const float* __restrict__ b2f,
    float* __restrict__ x1, float* __restrict__ x2,
    const float* __restrict__ out_w, const float* __restrict__ out_b,
    float* __restrict__ y, int do_out)
{
    __shared__ unsigned cA1[1024];          // 4 KB: combine h|m; later LN h|m
    __shared__ unsigned short cA2h[1024];   // 2 KB: combine l; later LN l
    __shared__ unsigned gA1[4096];          // 16 KB: gelu h|m per wave; later red
    __shared__ unsigned short gA2h[4096];   // 8 KB: gelu l per wave
    __shared__ float lnS[64], lnQ[64];      // 0.5 KB
    float* red = (float*)gA1;

    int tid = threadIdx.x;
    int b  = blockIdx.x / 80;
    int t0 = (blockIdx.x % 80) * 16;
    int w = tid >> 6, lane = tid & 63;
    int quad = lane >> 4, col = lane & 15;
    int cg = w*16 + col;

    float x1pre[4], x2pre[4];
    #pragma unroll
    for (int reg=0; reg<4; reg++){
        size_t xi = ((size_t)b*LSEQ + t0 + quad*4 + reg)*DM + cg;
        x1pre[reg] = x1[xi];
        x2pre[reg] = x2[xi];
    }
    float wb_pre  = wo_b[cg];
    float gv_pre  = g2[cg];
    float bv_pre  = b2t[cg];
    float bbf_pre = b2f[cg];
    float ow_pre  = out_w[cg];
    float b1v[4];
    #pragma unroll
    for (int ntl=0; ntl<4; ntl++) b1v[ntl] = b1[(w*4 + ntl)*16 + col];

    {
        int tok = tid >> 4;
        int dg  = tid & 15;
        int d0  = dg * 4;
        int kt  = dg >> 2;
        int t = t0 + tok;
        int bh = b*NHEADS + kt;
        float sl[4];
        #pragma unroll
        for (int nh=0; nh<4; nh++) sl[nh] = slog[((size_t)bh*NHASH + nh)*LSEQ + t];
        float mx = fmaxf(fmaxf(sl[0],sl[1]), fmaxf(sl[2],sl[3]));
        float wgt[4]; float wsum = 0.f;
        #pragma unroll
        for (int nh=0; nh<4; nh++){ wgt[nh] = __expf(sl[nh]-mx); wsum += wgt[nh]; }
        float iv = 1.f/wsum;
        float a4[4] = {0.f,0.f,0.f,0.f};
        #pragma unroll
        for (int nh=0; nh<4; nh++){
            float4 oh = *(const float4*)&o_hash[(((size_t)bh*NHASH + nh)*LSEQ + t)*DHD + (d0 & 15)];
            float wn = wgt[nh]*iv;
            a4[0] += wn*oh.x; a4[1] += wn*oh.y; a4[2] += wn*oh.z; a4[3] += wn*oh.w;
        }
        int sw = (tok & 7) << 2;
        unsigned cw1[4], lw[4];
        #pragma unroll
        for (int i=0;i<4;i++) split_hml(a4[i], cw1[i], lw[i]);
        *(uint4*)&cA1[tok*64 + (d0 ^ sw)] = *(uint4*)cw1;
        uint2 lp;
        lp.x = lw[0] | (lw[1]<<16);
        lp.y = lw[2] | (lw[3]<<16);
        *(uint2*)&cA2h[tok*64 + (d0 ^ sw)] = lp;
    }
    __syncthreads();
    FU4 aA1[4], aA2[4];
    {
        int sw = (col & 7) << 2;
        #pragma unroll
        for (int kt=0; kt<4; kt++){
            int word = (kt*16 + quad*4) ^ sw;
            aA1[kt].v = *(const uint4*)&cA1[col*64 + word];
            uint2 zl = *(const uint2*)&cA2h[col*64 + word];
            aA2[kt].v.x = __builtin_amdgcn_perm(zl.x, aA1[kt].v.x, 0x05040100u);
            aA2[kt].v.y = __builtin_amdgcn_perm(zl.x, aA1[kt].v.y, 0x07060100u);
            aA2[kt].v.z = __builtin_amdgcn_perm(zl.y, aA1[kt].v.z, 0x05040100u);
            aA2[kt].v.w = __builtin_amdgcn_perm(zl.y, aA1[kt].v.w, 0x07060100u);
        }
    }

    frag_c awo = {0.f,0.f,0.f,0.f};
    #pragma unroll
    for (int kt=0; kt<4; kt++){
        FU4 B1, B2, B3;
        int bidx = ((kt*4 + w)*16 + col)*16 + quad*4;
        B1.v = *(const uint4*)&wo_s[bidx];
        B2.v = rot16v(B1.v);
        B3.v = *(const uint4*)&wo_s[bidx + 4096];
        awo = __builtin_amdgcn_mfma_f32_16x16x32_bf16(aA1[kt].f, B1.f, awo, 0, 0, 0);
        awo = __builtin_amdgcn_mfma_f32_16x16x32_bf16(aA1[kt].f, B2.f, awo, 0, 0, 0);
        awo = __builtin_amdgcn_mfma_f32_16x16x32_bf16(aA2[kt].f, B3.f, awo, 0, 0, 0);
    }
    float x1n[4];
    float s1[4], s2[4];
    {
        #pragma unroll
        for (int reg=0; reg<4; reg++){
            int rg = t0 + quad*4 + reg;
            size_t xi = ((size_t)b*LSEQ + rg)*DM + cg;
            float xv = x1pre[reg] + awo[reg] + wb_pre;
            x1[xi] = xv;
            x1n[reg] = xv;
            s1[reg] = xv; s2[reg] = xv*xv;
        }
    }
    #pragma unroll
    for (int reg=0; reg<4; reg++){
        float a = s1[reg], q = s2[reg];
        a += __shfl_xor(a,1); a += __shfl_xor(a,2); a += __shfl_xor(a,4); a += __shfl_xor(a,8);
        q += __shfl_xor(q,1); q += __shfl_xor(q,2); q += __shfl_xor(q,4); q += __shfl_xor(q,8);
        s1[reg] = a; s2[reg] = q;
    }
    if (col == 0) {
        #pragma unroll
        for (int reg=0; reg<4; reg++){
            lnS[w*16 + quad*4 + reg] = s1[reg];
            lnQ[w*16 + quad*4 + reg] = s2[reg];
        }
    }
    __syncthreads();   // also orders aA reads (above) before LN writes (below) into cA
    float mean[4], rstd[4];
    #pragma unroll
    for (int reg=0; reg<4; reg++){
        int tok = quad*4 + reg;
        float a = lnS[tok] + lnS[16+tok] + lnS[32+tok] + lnS[48+tok];
        float q = lnQ[tok] + lnQ[16+tok] + lnQ[32+tok] + lnQ[48+tok];
        mean[reg] = a*(1.f/64.f);
        float var = q*(1.f/64.f) - mean[reg]*mean[reg];
        rstd[reg] = 1.f/sqrtf(var + 1e-5f);
    }
    {
        #pragma unroll
        for (int reg=0; reg<4; reg++){
            int row = quad*4 + reg;
            float xv = (x1n[reg]-mean[reg])*rstd[reg]*gv_pre + bv_pre;
            unsigned hm_, l_;
            split_hml(xv, hm_, l_);
            int word = cg ^ ((row & 7) << 2);
            cA1[row*64 + word] = hm_;
            cA2h[row*64 + word] = (unsigned short)l_;
        }
    }
    __syncthreads();
    FU4 xa1[4], xa2[4];
    {
        int sw = (col & 7) << 2;
        #pragma unroll
        for (int kt=0; kt<4; kt++){
            int word = (kt*16 + quad*4) ^ sw;
            xa1[kt].v = *(const uint4*)&cA1[col*64 + word];
            uint2 zl = *(const uint2*)&cA2h[col*64 + word];
            xa2[kt].v.x = __builtin_amdgcn_perm(zl.x, xa1[kt].v.x, 0x05040100u);
            xa2[kt].v.y = __builtin_amdgcn_perm(zl.x, xa1[kt].v.y, 0x07060100u);
            xa2[kt].v.z = __builtin_amdgcn_perm(zl.y, xa1[kt].v.z, 0x05040100u);
            xa2[kt].v.w = __builtin_amdgcn_perm(zl.y, xa1[kt].v.w, 0x07060100u);
        }
    }

    unsigned* myg1 = gA1 + w*1024;
    unsigned short* myg2h = gA2h + w*1024;
    #pragma unroll
    for (int ntl=0; ntl<4; ntl++){
        int nt = w*4 + ntl;
        frag_c a = {0.f,0.f,0.f,0.f};
        #pragma unroll
        for (int kt=0; kt<4; kt++){
            FU4 B1, B2, B3;
            int bidx = ((kt*16 + nt)*16 + col)*16 + quad*4;
            B1.v = *(const uint4*)&w1_s[bidx];
            B2.v = rot16v(B1.v);
            B3.v = *(const uint4*)&w1_s[bidx + 16384];
            a = __builtin_amdgcn_mfma_f32_16x16x32_bf16(xa1[kt].f, B1.f, a, 0, 0, 0);
            a = __builtin_amdgcn_mfma_f32_16x16x32_bf16(xa1[kt].f, B2.f, a, 0, 0, 0);
            a = __builtin_amdgcn_mfma_f32_16x16x32_bf16(xa2[kt].f, B3.f, a, 0, 0, 0);
        }
        float bb = b1v[ntl];
        #pragma unroll
        for (int reg=0; reg<4; reg++){
            float xx = a[reg] + bb;
            float ge = gelu_fast(xx);
            unsigned hm_, l_;
            split_hml(ge, hm_, l_);
            int row = quad*4 + reg;
            int word = (ntl*16 + col) ^ ((row & 7) << 2);
            myg1[row*64 + word] = hm_;
            myg2h[row*64 + word] = (unsigned short)l_;
        }
    }
    frag_c aw2[4] = {{0,0,0,0},{0,0,0,0},{0,0,0,0},{0,0,0,0}};
    {
        int sw = (col & 7) << 2;
        #pragma unroll
        for (int kt2=0; kt2<4; kt2++){
            FU4 A1, A2;
            int word = (kt2*16 + quad*4) ^ sw;
            A1.v = *(const uint4*)&myg1[col*64 + word];
            uint2 zl = *(const uint2*)&myg2h[col*64 + word];
            A2.v.x = __builtin_amdgcn_perm(zl.x, A1.v.x, 0x05040100u);
            A2.v.y = __builtin_amdgcn_perm(zl.x, A1.v.y, 0x07060100u);
            A2.v.z = __builtin_amdgcn_perm(zl.y, A1.v.z, 0x05040100u);
            A2.v.w = __builtin_amdgcn_perm(zl.y, A1.v.w, 0x07060100u);
            int kg = w*4 + kt2;
            #pragma unroll
            for (int nt2=0; nt2<4; nt2++){
                FU4 B1, B2, B3;
                int bidx = ((kg*4 + nt2)*16 + col)*16 + quad*4;
                B1.v = *(const uint4*)&w2_s[bidx];
                B2.v = rot16v(B1.v);
                B3.v = *(const uint4*)&w2_s[bidx + 16384];
                aw2[nt2] = __builtin_amdgcn_mfma_f32_16x16x32_bf16(A1.f, B1.f, aw2[nt2], 0, 0, 0);
                aw2[nt2] = __builtin_amdgcn_mfma_f32_16x16x32_bf16(A1.f, B2.f, aw2[nt2], 0, 0, 0);
                aw2[nt2] = __builtin_amdgcn_mfma_f32_16x16x32_bf16(A2.f, B3.f, aw2[nt2], 0, 0, 0);
            }
        }
    }
    // no barrier: red region of wave w aliases only wave w's own myg1 region (same-wave order)
    #pragma unroll
    for (int nt2=0; nt2<4; nt2++)
        #pragma unroll
        for (int reg=0; reg<4; reg++)
            red[((w*4 + nt2)*4 + reg)*64 + lane] = aw2[nt2][reg];
    __syncthreads();   // cross-wave: red read below spans all waves' regions
    float x2f[4];
    {
        #pragma unroll
        for (int reg=0; reg<4; reg++){
            float v = red[((0*4 + w)*4 + reg)*64 + lane]
                    + red[((1*4 + w)*4 + reg)*64 + lane]
                    + red[((2*4 + w)*4 + reg)*64 + lane]
                    + red[((3*4 + w)*4 + reg)*64 + lane];
            int rg = t0 + quad*4 + reg;
            size_t xi = ((size_t)b*LSEQ + rg)*DM + cg;
            float nv = x2pre[reg] + v + bbf_pre;
            x2[xi] = nv;
            x2f[reg] = nv;
        }
    }
    if (do_out) {
        float part[4];
        #pragma unroll
        for (int reg=0; reg<4; reg++){
            float p = (x1n[reg] + x2f[reg]) * 0.5f * ow_pre;
            p += __shfl_xor(p,1); p += __shfl_xor(p,2); p += __shfl_xor(p,4); p += __shfl_xor(p,8);
            part[reg] = p;
        }
        __syncthreads();
        if (col == 0) {
            #pragma unroll
            for (int reg=0; reg<4; reg++)
                lnS[w*16 + quad*4 + reg] = part[reg];
        }
        __syncthreads();
        if (tid < 16) {
            int t = t0 + tid;
            if (t < L0SEQ) {
                float v2 = lnS[tid] + lnS[16+tid] + lnS[32+tid] + lnS[48+tid];
                y[(size_t)b*L0SEQ + t] = v2 + out_b[0];
            }
        }
    }
}

extern "C" void kernel_launch(void* const* d_in, const int* in_sizes, int n_in,
                              void* d_out, int out_size, void* d_ws, size_t ws_size,
                              hipStream_t stream)
{
    const float* wave  = (const float*)d_in[0];
    const float* in_w  = (const float*)d_in[1];
    const float* in_b  = (const float*)d_in[2];
    const float* ln1_g = (const float*)d_in[3];
    const float* ln1_b = (const float*)d_in[4];
    const float* wqk   = (const float*)d_in[5];
    const float* wv    = (const float*)d_in[6];
    const float* wo_w  = (const float*)d_in[7];
    const float* wo_b  = (const float*)d_in[8];
    const float* rot   = (const float*)d_in[9];
    const float* ln2_g = (const float*)d_in[10];
    const float* ln2_b = (const float*)d_in[11];
    const float* w1    = (const float*)d_in[12];
    const float* b1    = (const float*)d_in[13];
    const float* w2    = (const float*)d_in[14];
    const float* b2    = (const float*)d_in[15];
    const float* out_w = (const float*)d_in[16];
    const float* out_b = (const float*)d_in[17];
    float* y = (float*)d_out;

    float* ws = (float*)d_ws;
    float* x1      = ws;                       // XSZ f32
    float* x2      = x1 + XSZ;                 // XSZ f32
    unsigned* qkvs = (unsigned*)(x2 + XSZ);    // 4*QKSZ u32 (interleaved)
    float* o_hash  = (float*)(qkvs + 4*QKSZ);  // OHSZ f32
    float* slogb   = o_hash + OHSZ;            // SLSZ f32
    int* buckets   = (int*)(slogb + SLSZ);     // SLSZ int
    int* sorted    = buckets + SLSZ;           // SLSZ int
    unsigned* wsplit = (unsigned*)(sorted + SLSZ); // 294912 u32

    k_init<<<5696, 256, 0, stream>>>(wave, in_w, in_b, x1, x2, wo_w, w1, w2, wsplit);
    for (int layer = 0; layer < 4; layer++) {
        k_qkv<<<NBATCH*80, 256, 0, stream>>>(x2, ln1_g + layer*64, ln1_b + layer*64,
                                       wqk + layer*4096, wv + layer*4096, rot + layer*640,
                                       qkvs, buckets);
        k_sort<<<256, 256, 0, stream>>>(buckets, sorted);
        k_attn<<<NBH*NCHUNK, 256, 0, stream>>>(qkvs, sorted, o_hash, slogb);
        k_tail<<<NBATCH*LSEQ/16, 256, 0, stream>>>(o_hash, slogb,
                                        wsplit + layer*8192, wo_b + layer*64,
                                        ln2_g + layer*64, ln2_b + layer*64,
                                        wsplit + 32768 + layer*32768, b1 + layer*256,
                                        wsplit + 163840 + layer*32768, b2 + layer*64,
                                        x1, x2,
                                        out_w, out_b, y, (layer == 3) ? 1 : 0);
    }
}